// Round 13
// baseline (124.556 us; speedup 1.0000x reference)
//
#include <hip/hip_runtime.h>
#include <hip/hip_bf16.h>

using u16 = unsigned short;
using u16x8 = __attribute__((ext_vector_type(8))) unsigned short;
using s16x4 = __attribute__((ext_vector_type(4))) short;   // 4 bf16
using s16x8 = __attribute__((ext_vector_type(8))) short;   // 8 bf16 (4 VGPRs)
using f32x4 = __attribute__((ext_vector_type(4))) float;   // MFMA accum

__device__ __forceinline__ f32x4 mfma16(s16x8 a, s16x8 b, f32x4 c) {
    return __builtin_amdgcn_mfma_f32_16x16x32_bf16(a, b, c, 0, 0, 0);
}

__device__ __forceinline__ u16 f2bf(float f) {
    union { float f; unsigned u; } v; v.f = f;
    unsigned r = v.u + 0x7FFFu + ((v.u >> 16) & 1u);   // RNE
    return (u16)(r >> 16);
}

__device__ __forceinline__ unsigned cvt_pk_bf16(float lo, float hi) {
    unsigned r;
    asm("v_cvt_pk_bf16_f32 %0, %1, %2" : "=v"(r) : "v"(lo), "v"(hi));
    return r;
}

__device__ __forceinline__ float fast_exp2(float x) {
    float r;
    asm("v_exp_f32 %0, %1" : "=v"(r) : "v"(x));   // denorm underflow -> 0
    return r;
}

__device__ __forceinline__ unsigned pk2(u16 a, u16 b) {
    return (unsigned)a | ((unsigned)b << 16);
}

__device__ __forceinline__ float bf2f(u16 u) {
    union { unsigned u; float f; } v; v.u = ((unsigned)u) << 16;
    return v.f;
}

// async global -> LDS DMA, 16 B per lane; dest = lds_base + lane*16 (linear)
__device__ __forceinline__ void gload_lds16(const u16* g, u16* l) {
    __builtin_amdgcn_global_load_lds(
        (const __attribute__((address_space(1))) void*)g,
        (__attribute__((address_space(3))) void*)l, 16, 0, 0);
}

// ---------------------------------------------------------------------------
// 1) fp32 -> bf16 conversion of x and the 4 weight matrices (one launch).
// ---------------------------------------------------------------------------
__global__ __launch_bounds__(256) void conv_kernel(
    const float* __restrict__ s0, const float* __restrict__ s1,
    const float* __restrict__ s2, const float* __restrict__ s3,
    const float* __restrict__ s4,
    u16* __restrict__ d0, u16* __restrict__ d1, u16* __restrict__ d2,
    u16* __restrict__ d3, u16* __restrict__ d4)
{
    int i = blockIdx.x * 256 + threadIdx.x;
    const float* s; u16* d; int off;
    if (i < 524288)      { s = s0; d = d0; off = i; }
    else if (i < 573440) { s = s1; d = d1; off = i - 524288; }
    else if (i < 589824) { s = s2; d = d2; off = i - 573440; }
    else if (i < 655360) { s = s3; d = d3; off = i - 589824; }
    else                 { s = s4; d = d4; off = i - 655360; }
    float4 f = ((const float4*)s)[off];
    ushort4 u;
    u.x = f2bf(f.x); u.y = f2bf(f.y); u.z = f2bf(f.z); u.w = f2bf(f.w);
    ((ushort4*)d)[off] = u;
}

// ---------------------------------------------------------------------------
// Generic bf16 MFMA GEMM: out[M][N] = A[M][K] * W[N][K]^T (+bias) (+resid)
// Tile BM x 64. T4 pipeline: global_load_lds into 3-buffer XOR-swizzled LDS,
// counted vmcnt, ONE raw s_barrier per K-step. Per-operand strides; A may be
// split at k=256 (SPLIT).
// ---------------------------------------------------------------------------
template<int OUTMODE, bool SPLIT, bool RESID, bool BIAS, int BM>
__global__ __launch_bounds__(256) void gemm_kernel(
    const u16* __restrict__ A0, const u16* __restrict__ A1,
    const u16* __restrict__ W0, const float* __restrict__ bias,
    const float* __restrict__ resid, float* __restrict__ outf,
    u16* __restrict__ outb,
    int M, int N, int K, int lda0, int lda1, int ldw0, int ldo)
{
    constexpr int MS = BM / 32;            // m-subtiles per wave
    __shared__ u16 A_lds[3][BM][64];
    __shared__ u16 B_lds[3][64][64];
    const int tid = threadIdx.x;
    const int l = tid & 63, w = tid >> 6;
    const int lr = l & 15, lg = l >> 4;
    const int r7 = lr & 7;
    const int m0 = blockIdx.x * BM, n0 = blockIdx.y * 64;
    const int wm = (w >> 1) * (BM / 2), wn = (w & 1) * 32;

    const int lrow = l >> 3;
    const int swz = (l & 7) ^ lrow;            // logical 16B-slot for this lane
    const int arow = (BM / 4) * w + lrow;      // A rows: +8i
    const int brow = 16 * w + lrow;            // B rows: +8i

    #define STAGE_G(s, b)                                                     \
        do {                                                                  \
            int k0_ = 64 * (s);                                               \
            const u16* As_; int lda_; int ka_ = k0_;                          \
            if (SPLIT && k0_ >= 256) { As_ = A1; lda_ = lda1; ka_ = k0_ - 256; }\
            else { As_ = A0; lda_ = lda0; }                                   \
            _Pragma("unroll")                                                 \
            for (int i = 0; i < BM / 32; ++i)                                 \
                gload_lds16(As_ + (size_t)(m0 + arow + 8 * i) * lda_ + ka_ + swz * 8,\
                            &A_lds[b][(BM / 4) * w + 8 * i][0]);              \
            _Pragma("unroll")                                                 \
            for (int i = 0; i < 2; ++i)                                       \
                gload_lds16(W0 + (size_t)(n0 + brow + 8 * i) * ldw0 + k0_ + swz * 8,\
                            &B_lds[b][16 * w + 8 * i][0]);                    \
        } while (0)

    f32x4 acc[MS][2];
    #pragma unroll
    for (int i = 0; i < MS; ++i)
        #pragma unroll
        for (int j = 0; j < 2; ++j)
            acc[i][j] = (f32x4){0.f, 0.f, 0.f, 0.f};

    const int NS = K >> 6;
    int cur = 0, nxt = 1;
    STAGE_G(0, 0);

    for (int s = 0; s < NS; ++s) {
        if (s + 1 < NS) {
            STAGE_G(s + 1, nxt);
            if constexpr (BM == 128)
                asm volatile("s_waitcnt vmcnt(6)" ::: "memory");
            else
                asm volatile("s_waitcnt vmcnt(4)" ::: "memory");
        } else {
            asm volatile("s_waitcnt vmcnt(0)" ::: "memory");
        }
        __builtin_amdgcn_sched_barrier(0);
        __builtin_amdgcn_s_barrier();
        __builtin_amdgcn_sched_barrier(0);

        #pragma unroll
        for (int ks = 0; ks < 2; ++ks) {
            s16x8 af[MS], bfr[2];
            #pragma unroll
            for (int ms = 0; ms < MS; ++ms)
                af[ms] = *(const s16x8*)&A_lds[cur][wm + ms * 16 + lr]
                                              [((ks * 4 + lg) ^ r7) * 8];
            #pragma unroll
            for (int ns = 0; ns < 2; ++ns)
                bfr[ns] = *(const s16x8*)&B_lds[cur][wn + ns * 16 + lr]
                                               [((ks * 4 + lg) ^ r7) * 8];
            #pragma unroll
            for (int ms = 0; ms < MS; ++ms)
                #pragma unroll
                for (int ns = 0; ns < 2; ++ns)
                    acc[ms][ns] = mfma16(af[ms], bfr[ns], acc[ms][ns]);
        }
        cur = nxt;
        nxt = (nxt == 2) ? 0 : nxt + 1;
    }
    #undef STAGE_G

    #pragma unroll
    for (int ms = 0; ms < MS; ++ms) {
        #pragma unroll
        for (int ns = 0; ns < 2; ++ns) {
            int cg = n0 + wn + ns * 16 + lr;
            float bv = BIAS ? bias[cg] : 0.f;
            #pragma unroll
            for (int r = 0; r < 4; ++r) {
                int rg = m0 + wm + ms * 16 + lg * 4 + r;
                float val = acc[ms][ns][r] + bv;
                if (RESID) val += resid[(size_t)rg * N + cg];
                if (OUTMODE == 0) outf[(size_t)rg * ldo + cg] = val;
                else              outb[(size_t)rg * ldo + cg] = f2bf(val);
            }
        }
    }
}

// ---------------------------------------------------------------------------
// 3+4) Fused RoPE + V-transpose. Grid (64 n-blocks, 8 bh). Per block: 64 rows
// of head h. Writes Q,K (bf16 [bh][n][64], q scaled by 0.125*log2e) and Vt
// ([bh][64][n], PV-permuted: pos 32*kb+8*lg+j holds kv=32*kb+16*(j>>2)+4*lg+(j&3)).
// ---------------------------------------------------------------------------
__global__ __launch_bounds__(256) void rope_tv_kernel(
    const u16* __restrict__ qkv, const float* __restrict__ enc,
    u16* __restrict__ Qo, u16* __restrict__ Ko, u16* __restrict__ Vt)
{
    __shared__ u16 vt_lds[64][72];
    const int tid = threadIdx.x;
    const int bh = blockIdx.y, n0 = blockIdx.x * 64;
    const int b = bh >> 2, h = bh & 3;
    const float qs = 0.18033688011112042f;   // 0.125 * log2(e)

    #pragma unroll
    for (int it = 0; it < 8; ++it) {
        int task = it * 256 + tid;
        int r = task >> 5, t = task & 31;
        size_t grow = (size_t)(b * 4096 + n0 + r);
        const u16* base = qkv + grow * 768 + 3 * (h * 64) + 6 * t;
        ushort2 a01 = *(const ushort2*)(base);       // q0 k0
        ushort2 a23 = *(const ushort2*)(base + 2);   // v0 q1
        ushort2 a45 = *(const ushort2*)(base + 4);   // k1 v1
        float q0 = bf2f(a01.x), k0 = bf2f(a01.y);
        float q1 = bf2f(a23.y), k1 = bf2f(a45.x);
        const float* cb = enc + grow * 256 + h * 64 + 2 * t;
        float2 cosv = *(const float2*)cb;
        float2 sinv = *(const float2*)(cb + 2097152);
        float qr0 = (q0 * cosv.x - q1 * sinv.x) * qs;
        float qr1 = (q1 * cosv.y + q0 * sinv.y) * qs;
        float kr0 = k0 * cosv.x - k1 * sinv.x;
        float kr1 = k1 * cosv.y + k0 * sinv.y;
        size_t o = ((size_t)bh * 4096 + n0 + r) * 64 + 2 * t;
        *(unsigned*)(Qo + o) = cvt_pk_bf16(qr0, qr1);
        *(unsigned*)(Ko + o) = cvt_pk_bf16(kr0, kr1);
        vt_lds[r][2 * t]     = a23.x;
        vt_lds[r][2 * t + 1] = a45.y;
    }
    __syncthreads();
    #pragma unroll
    for (int i = 0; i < 2; ++i) {
        int c = tid + 256 * i;
        int d = c >> 3, ng = c & 7;
        int kb = ng >> 2, lg4 = ng & 3;
        int base = 32 * kb + 4 * lg4;
        unsigned w0 = pk2(vt_lds[base +  0][d], vt_lds[base +  1][d]);
        unsigned w1 = pk2(vt_lds[base +  2][d], vt_lds[base +  3][d]);
        unsigned w2 = pk2(vt_lds[base + 16][d], vt_lds[base + 17][d]);
        unsigned w3 = pk2(vt_lds[base + 18][d], vt_lds[base + 19][d]);
        uint4 o4 = make_uint4(w0, w1, w2, w3);
        *(uint4*)(Vt + ((size_t)bh * 64 + d) * 4096 + n0 + ng * 8) = o4;
    }
}

// ---------------------------------------------------------------------------
// 5) Flash attention, 64 q-rows/wave (256/block). kv-split x4, swapped QK^T,
// fixed-shift softmax (C-init -24), MFMA row-sum. Per-kt two kb-passes
// (kv 0-31 / 32-63) to cap register liveness. Static 2-buffer unroll,
// setprio on MFMA clusters. LDS reads per unit work halved vs 32 q/wave.
// ---------------------------------------------------------------------------
__global__ __launch_bounds__(256) void attn_kernel(
    const u16* __restrict__ Qp, const u16* __restrict__ Kp,
    const u16* __restrict__ Vtp, u16* __restrict__ Opart,
    float* __restrict__ Ssum)
{
    __shared__ u16 K_lds[2][64][64];   // 16 KB, linear
    __shared__ u16 V_lds[2][64][64];   // 16 KB, linear ([d][kv-permuted])
    const int tid = threadIdx.x;
    const int l = tid & 63, w = tid >> 6;
    const int lr = l & 15, lg = l >> 4;
    const int r7 = lr & 7;
    const int bh = blockIdx.y, z = blockIdx.z;
    const int n0 = blockIdx.x * 256 + w * 64;   // this wave's 64 q-rows

    const u16* Qb = Qp + ((size_t)bh * 4096 + n0) * 64;
    s16x8 qf[4][2];
    #pragma unroll
    for (int qt = 0; qt < 4; ++qt)
        #pragma unroll
        for (int dh = 0; dh < 2; ++dh)
            qf[qt][dh] = *(const s16x8*)(Qb + (qt * 16 + lr) * 64 + dh * 32 + lg * 8);

    const u16* Kb = Kp + (size_t)bh * 4096 * 64 + (size_t)z * 1024 * 64;
    const u16* Vb = Vtp + (size_t)bh * 64 * 4096 + z * 1024;

    const int xs0 = (lg ^ r7) * 8;          // loop-invariant LDS slot offsets
    const int xs1 = ((4 + lg) ^ r7) * 8;

    const int swz = (l & 7) ^ ((l >> 3) & 7);
    const int row0 = 16 * w + (l >> 3);
    const size_t koff0 = (size_t)row0 * 64 + swz * 8;
    const size_t koff1 = (size_t)(row0 + 8) * 64 + swz * 8;
    const size_t voff0 = (size_t)row0 * 4096 + swz * 8;
    const size_t voff1 = (size_t)(row0 + 8) * 4096 + swz * 8;

    #define STAGE(kt, b)                                                      \
        do {                                                                  \
            const u16* ks_ = Kb + (size_t)(kt) * 4096;                        \
            const u16* vs_ = Vb + (size_t)(kt) * 64;                          \
            gload_lds16(ks_ + koff0, &K_lds[b][16 * w][0]);                   \
            gload_lds16(ks_ + koff1, &K_lds[b][16 * w + 8][0]);               \
            gload_lds16(vs_ + voff0, &V_lds[b][16 * w][0]);                   \
            gload_lds16(vs_ + voff1, &V_lds[b][16 * w + 8][0]);               \
        } while (0)

    f32x4 O[4][4];
    #pragma unroll
    for (int qt = 0; qt < 4; ++qt)
        #pragma unroll
        for (int dv = 0; dv < 4; ++dv)
            O[qt][dv] = (f32x4){0.f, 0.f, 0.f, 0.f};
    f32x4 ssum[4];
    #pragma unroll
    for (int qt = 0; qt < 4; ++qt) ssum[qt] = (f32x4){0.f, 0.f, 0.f, 0.f};
    s16x8 ones;
    #pragma unroll
    for (int j = 0; j < 8; ++j) ones[j] = (short)0x3F80;   // bf16 1.0

    STAGE(0, 0);
    __syncthreads();   // drains DMA + barrier: buf0 ready

    // One kb-pass: kv block 32*KB..32*KB+31 (v4 = 2KB, 2KB+1) of buffer CB.
    #define KBPASS(CB, KB)                                                    \
        do {                                                                  \
            const int rA = (2 * (KB)) * 16 + lr;                              \
            const int rB = (2 * (KB) + 1) * 16 + lr;                          \
            s16x8 kfA0 = *(const s16x8*)&K_lds[CB][rA][xs0];                  \
            s16x8 kfA1 = *(const s16x8*)&K_lds[CB][rA][xs1];                  \
            s16x8 kfB0 = *(const s16x8*)&K_lds[CB][rB][xs0];                  \
            s16x8 kfB1 = *(const s16x8*)&K_lds[CB][rB][xs1];                  \
            f32x4 SA[4], SB[4];                                               \
            __builtin_amdgcn_s_setprio(1);                                    \
            _Pragma("unroll")                                                 \
            for (int qt = 0; qt < 4; ++qt) {                                  \
                f32x4 za = (f32x4){-24.f, -24.f, -24.f, -24.f};               \
                za = mfma16(kfA0, qf[qt][0], za);                             \
                za = mfma16(kfA1, qf[qt][1], za);                             \
                SA[qt] = za;                                                  \
                f32x4 zb = (f32x4){-24.f, -24.f, -24.f, -24.f};               \
                zb = mfma16(kfB0, qf[qt][0], zb);                             \
                zb = mfma16(kfB1, qf[qt][1], zb);                             \
                SB[qt] = zb;                                                  \
            }                                                                 \
            __builtin_amdgcn_s_setprio(0);                                    \
            s16x8 pa[4];                                                      \
            _Pragma("unroll")                                                 \
            for (int qt = 0; qt < 4; ++qt) {                                  \
                union { unsigned u[4]; s16x8 v; } pu;                         \
                pu.u[0] = cvt_pk_bf16(fast_exp2(SA[qt][0]),                   \
                                      fast_exp2(SA[qt][1]));                  \
                pu.u[1] = cvt_pk_bf16(fast_exp2(SA[qt][2]),                   \
                                      fast_exp2(SA[qt][3]));                  \
                pu.u[2] = cvt_pk_bf16(fast_exp2(SB[qt][0]),                   \
                                      fast_exp2(SB[qt][1]));                  \
                pu.u[3] = cvt_pk_bf16(fast_exp2(SB[qt][2]),                   \
                                      fast_exp2(SB[qt][3]));                  \
                pa[qt] = pu.v;                                                \
            }                                                                 \
            const int vs_ = (KB) ? xs1 : xs0;                                 \
            s16x8 vf0 = *(const s16x8*)&V_lds[CB][lr][vs_];                   \
            s16x8 vf1 = *(const s16x8*)&V_lds[CB][16 + lr][vs_];              \
            s16x8 vf2 = *(const s16x8*)&V_lds[CB][32 + lr][vs_];              \
            s16x8 vf3 = *(const s16x8*)&V_lds[CB][48 + lr][vs_];              \
            __builtin_amdgcn_s_setprio(1);                                    \
            _Pragma("unroll")                                                 \
            for (int qt = 0; qt < 4; ++qt) {                                  \
                O[qt][0] = mfma16(pa[qt], vf0, O[qt][0]);                     \
                O[qt][1] = mfma16(pa[qt], vf1, O[qt][1]);                     \
                O[qt][2] = mfma16(pa[qt], vf2, O[qt][2]);                     \
                O[qt][3] = mfma16(pa[qt], vf3, O[qt][3]);                     \
                ssum[qt] = mfma16(pa[qt], ones, ssum[qt]);                    \
            }                                                                 \
            __builtin_amdgcn_s_setprio(0);                                    \
        } while (0)

    #define PHASE(kt, CB, DO_STAGE)                                           \
        do {                                                                  \
            if (DO_STAGE) STAGE((kt) + 1, (CB) ^ 1);                          \
            KBPASS(CB, 0);                                                    \
            KBPASS(CB, 1);                                                    \
            __syncthreads();                                                  \
        } while (0)

    #pragma unroll 1
    for (int kt = 0; kt < 16; kt += 2) {
        PHASE(kt, 0, true);
        PHASE(kt + 1, 1, kt < 14);
    }
    #undef PHASE
    #undef KBPASS
    #undef STAGE

    // epilogue: unnormalized O (bf16) + s; combine normalizes.
    u16* Ob = Opart + ((size_t)(z * 8 + bh) * 4096 + n0) * 64;
    #pragma unroll
    for (int qt = 0; qt < 4; ++qt)
        #pragma unroll
        for (int dv = 0; dv < 4; ++dv)
            #pragma unroll
            for (int r = 0; r < 4; ++r)
                Ob[(size_t)(qt * 16 + 4 * lg + r) * 64 + 16 * dv + lr] =
                    f2bf(O[qt][dv][r]);
    if (lr == 0) {
        #pragma unroll
        for (int qt = 0; qt < 4; ++qt) {
            float4 sv = make_float4(ssum[qt][0], ssum[qt][1],
                                    ssum[qt][2], ssum[qt][3]);
            *(float4*)&Ssum[(size_t)(z * 8 + bh) * 4096 + n0 + qt * 16 + 4 * lg] = sv;
        }
    }
}

// ---------------------------------------------------------------------------
// 5b) Combine the four kv-split partials -> ctx (bf16 [b][n][256]).
// ---------------------------------------------------------------------------
__global__ __launch_bounds__(256) void combine_kernel(
    const u16* __restrict__ Opart, const float* __restrict__ Ssum,
    u16* __restrict__ ctx)
{
    int idx = blockIdx.x * 256 + threadIdx.x;    // 262144 = 32768 rows * 8 dc
    int rr = idx >> 3;            // bh*4096 + n
    int dc = (idx & 7) * 8;
    float s = Ssum[rr] + Ssum[32768 + rr] + Ssum[65536 + rr] + Ssum[98304 + rr];
    float inv = 1.f / s;
    float acc[8];
    #pragma unroll
    for (int j = 0; j < 8; ++j) acc[j] = 0.f;
    #pragma unroll
    for (int z = 0; z < 4; ++z) {
        u16x8 ov = *(const u16x8*)(Opart + ((size_t)z * 32768 + rr) * 64 + dc);
        #pragma unroll
        for (int j = 0; j < 8; ++j) acc[j] += bf2f(ov[j]);
    }
    #pragma unroll
    for (int j = 0; j < 8; ++j) acc[j] *= inv;
    int bh = rr >> 12, n = rr & 4095;
    int b = bh >> 2, h = bh & 3;
    uint4 o4 = make_uint4(cvt_pk_bf16(acc[0], acc[1]), cvt_pk_bf16(acc[2], acc[3]),
                          cvt_pk_bf16(acc[4], acc[5]), cvt_pk_bf16(acc[6], acc[7]));
    *(uint4*)(ctx + ((size_t)(b * 4096 + n)) * 256 + h * 64 + dc) = o4;
}

// ---------------------------------------------------------------------------
// 8) LayerNorm(512) + exact GELU, wave per row; bf16 in (y1), bf16 out.
// ---------------------------------------------------------------------------
__global__ __launch_bounds__(256) void ln_gelu_kernel(
    const u16* __restrict__ y, const float* __restrict__ g,
    const float* __restrict__ bta, u16* __restrict__ o)
{
    int row = blockIdx.x * 4 + (threadIdx.x >> 6);
    int l = threadIdx.x & 63;
    const u16* yr = y + (size_t)row * 512 + l * 8;
    u16x8 uv = *(const u16x8*)yr;
    float v[8];
    #pragma unroll
    for (int j = 0; j < 8; ++j) v[j] = bf2f(uv[j]);
    float s = 0.f;
    #pragma unroll
    for (int j = 0; j < 8; ++j) s += v[j];
    #pragma unroll
    for (int off = 32; off; off >>= 1) s += __shfl_xor(s, off, 64);
    float mu = s * (1.f / 512.f);
    float q = 0.f;
    #pragma unroll
    for (int j = 0; j < 8; ++j) { float t = v[j] - mu; q += t * t; }
    #pragma unroll
    for (int off = 32; off; off >>= 1) q += __shfl_xor(q, off, 64);
    float rs = rsqrtf(q * (1.f / 512.f) + 1e-5f);
    u16 u[8];
    #pragma unroll
    for (int j = 0; j < 8; ++j) {
        float t = (v[j] - mu) * rs * g[l * 8 + j] + bta[l * 8 + j];
        t = t * 0.5f * (1.f + erff(t * 0.70710678118654752f));
        u[j] = f2bf(t);
    }
    uint4 o4 = make_uint4(pk2(u[0], u[1]), pk2(u[2], u[3]),
                          pk2(u[4], u[5]), pk2(u[6], u[7]));
    *(uint4*)(o + (size_t)row * 512 + l * 8) = o4;
}

// ---------------------------------------------------------------------------
extern "C" void kernel_launch(void* const* d_in, const int* in_sizes, int n_in,
                              void* d_out, int out_size, void* d_ws, size_t ws_size,
                              hipStream_t stream) {
    (void)in_sizes; (void)n_in; (void)out_size; (void)ws_size;
    const float* x    = (const float*)d_in[0];
    const float* enc  = (const float*)d_in[1];
    const float* wqkv = (const float*)d_in[2];
    const float* bqkv = (const float*)d_in[3];
    const float* wout = (const float*)d_in[4];
    const float* bout = (const float*)d_in[5];
    const float* w1   = (const float*)d_in[6];
    const float* b1   = (const float*)d_in[7];
    const float* lng  = (const float*)d_in[8];
    const float* lnb  = (const float*)d_in[9];
    const float* w2   = (const float*)d_in[10];
    const float* b2   = (const float*)d_in[11];
    float* out = (float*)d_out;
    char* ws = (char*)d_ws;

    u16*   xb    = (u16*)(ws + 0);              // 4 MB   bf16 x [8192][256]
    u16*   wqkvb = (u16*)(ws + 4194304);        // 384 KB
    u16*   woutb = (u16*)(ws + 4587520);        // 128 KB
    u16*   w1b   = (u16*)(ws + 4718592);        // 512 KB
    u16*   w2b   = (u16*)(ws + 5242880);        // 256 KB
    u16*   qkvb  = (u16*)(ws + 5505024);        // 12 MB  bf16 qkv [8192][768]
    u16*   OpartB= (u16*)(ws + 5505024);        // 16 MB  (reuse after rope_tv)
    u16*   y1bf  = (u16*)(ws + 5505024);        // 8 MB   (reuse after combine)
    float* Ssum  = (float*)(ws + 22282240);     // 512 KB
    u16*   q     = (u16*)(ws + 30670848);       // 4 MB  [bh][n][64]
    u16*   k     = (u16*)(ws + 34865152);       // 4 MB
    u16*   vt    = (u16*)(ws + 43253760);       // 4 MB  [bh][64][n] (permuted)
    u16*   ybf   = q;                           // reuse q region after attn
    u16*   ctx   = (u16*)(ws + 47448064);       // 4 MB
    u16*   msg   = (u16*)(ws + 51642368);       // 4 MB

    conv_kernel<<<2688, 256, 0, stream>>>(x, wqkv, wout, w1, w2,
                                          xb, wqkvb, woutb, w1b, w2b);
    // qkv = x @ Wqkv^T + b  (bf16 out)
    gemm_kernel<1, false, false, true, 128><<<dim3(64, 12), 256, 0, stream>>>(
        xb, nullptr, wqkvb, bqkv, nullptr, nullptr, qkvb,
        8192, 768, 256, 256, 0, 256, 768);
    rope_tv_kernel<<<dim3(64, 8), 256, 0, stream>>>(qkvb, enc, q, k, vt);
    attn_kernel<<<dim3(16, 8, 4), 256, 0, stream>>>(q, k, vt, OpartB, Ssum);
    combine_kernel<<<1024, 256, 0, stream>>>(OpartB, Ssum, ctx);
    // msg = ctx @ out_w^T + out_b  (bf16 out)
    gemm_kernel<1, false, false, true, 64><<<dim3(128, 4), 256, 0, stream>>>(
        ctx, nullptr, woutb, bout, nullptr, nullptr, msg,
        8192, 256, 256, 256, 0, 256, 256);
    // y1 = [x | msg] @ ffn1^T + b1  (bf16 out)
    gemm_kernel<1, true, false, true, 128><<<dim3(64, 8), 256, 0, stream>>>(
        xb, msg, w1b, b1, nullptr, nullptr, y1bf,
        8192, 512, 512, 256, 256, 512, 512);
    ln_gelu_kernel<<<2048, 256, 0, stream>>>(y1bf, lng, lnb, ybf);
    // out = x + ybf @ ffn2^T + b2  (fp32 out, residual)
    gemm_kernel<0, false, true, true, 64><<<dim3(128, 4), 256, 0, stream>>>(
        ybf, nullptr, w2b, b2, x, out, nullptr,
        8192, 256, 512, 512, 0, 512, 256);
}

// Round 14
// 122.911 us; speedup vs baseline: 1.0134x; 1.0134x over previous
//
#include <hip/hip_runtime.h>
#include <hip/hip_bf16.h>

using u16 = unsigned short;
using u16x8 = __attribute__((ext_vector_type(8))) unsigned short;
using s16x4 = __attribute__((ext_vector_type(4))) short;   // 4 bf16
using s16x8 = __attribute__((ext_vector_type(8))) short;   // 8 bf16 (4 VGPRs)
using f32x4 = __attribute__((ext_vector_type(4))) float;   // MFMA accum

__device__ __forceinline__ f32x4 mfma16(s16x8 a, s16x8 b, f32x4 c) {
    return __builtin_amdgcn_mfma_f32_16x16x32_bf16(a, b, c, 0, 0, 0);
}

__device__ __forceinline__ u16 f2bf(float f) {
    union { float f; unsigned u; } v; v.f = f;
    unsigned r = v.u + 0x7FFFu + ((v.u >> 16) & 1u);   // RNE
    return (u16)(r >> 16);
}

__device__ __forceinline__ unsigned cvt_pk_bf16(float lo, float hi) {
    unsigned r;
    asm("v_cvt_pk_bf16_f32 %0, %1, %2" : "=v"(r) : "v"(lo), "v"(hi));
    return r;
}

__device__ __forceinline__ float fast_exp2(float x) {
    float r;
    asm("v_exp_f32 %0, %1" : "=v"(r) : "v"(x));   // denorm underflow -> 0
    return r;
}

__device__ __forceinline__ unsigned pk2(u16 a, u16 b) {
    return (unsigned)a | ((unsigned)b << 16);
}

__device__ __forceinline__ float bf2f(u16 u) {
    union { unsigned u; float f; } v; v.u = ((unsigned)u) << 16;
    return v.f;
}

// async global -> LDS DMA, 16 B per lane; dest = lds_base + lane*16 (linear)
__device__ __forceinline__ void gload_lds16(const u16* g, u16* l) {
    __builtin_amdgcn_global_load_lds(
        (const __attribute__((address_space(1))) void*)g,
        (__attribute__((address_space(3))) void*)l, 16, 0, 0);
}

// ---------------------------------------------------------------------------
// 1) fp32 -> bf16 conversion of x and the 4 weight matrices (one launch).
// ---------------------------------------------------------------------------
__global__ __launch_bounds__(256) void conv_kernel(
    const float* __restrict__ s0, const float* __restrict__ s1,
    const float* __restrict__ s2, const float* __restrict__ s3,
    const float* __restrict__ s4,
    u16* __restrict__ d0, u16* __restrict__ d1, u16* __restrict__ d2,
    u16* __restrict__ d3, u16* __restrict__ d4)
{
    int i = blockIdx.x * 256 + threadIdx.x;
    const float* s; u16* d; int off;
    if (i < 524288)      { s = s0; d = d0; off = i; }
    else if (i < 573440) { s = s1; d = d1; off = i - 524288; }
    else if (i < 589824) { s = s2; d = d2; off = i - 573440; }
    else if (i < 655360) { s = s3; d = d3; off = i - 589824; }
    else                 { s = s4; d = d4; off = i - 655360; }
    float4 f = ((const float4*)s)[off];
    ushort4 u;
    u.x = f2bf(f.x); u.y = f2bf(f.y); u.z = f2bf(f.z); u.w = f2bf(f.w);
    ((ushort4*)d)[off] = u;
}

// ---------------------------------------------------------------------------
// Generic bf16 MFMA GEMM: out[M][N] = A[M][K] * W[N][K]^T (+bias) (+resid)
// Tile BM x 64. T4 pipeline: global_load_lds into 3-buffer XOR-swizzled LDS,
// counted vmcnt, ONE raw s_barrier per K-step. A may be split at k=256.
// ---------------------------------------------------------------------------
template<int OUTMODE, bool SPLIT, bool RESID, bool BIAS, int BM>
__global__ __launch_bounds__(256) void gemm_kernel(
    const u16* __restrict__ A0, const u16* __restrict__ A1,
    const u16* __restrict__ W0, const float* __restrict__ bias,
    const float* __restrict__ resid, float* __restrict__ outf,
    u16* __restrict__ outb,
    int M, int N, int K, int lda0, int lda1, int ldw0, int ldo)
{
    constexpr int MS = BM / 32;            // m-subtiles per wave
    __shared__ u16 A_lds[3][BM][64];
    __shared__ u16 B_lds[3][64][64];
    const int tid = threadIdx.x;
    const int l = tid & 63, w = tid >> 6;
    const int lr = l & 15, lg = l >> 4;
    const int r7 = lr & 7;
    const int m0 = blockIdx.x * BM, n0 = blockIdx.y * 64;
    const int wm = (w >> 1) * (BM / 2), wn = (w & 1) * 32;

    const int lrow = l >> 3;
    const int swz = (l & 7) ^ lrow;            // logical 16B-slot for this lane
    const int arow = (BM / 4) * w + lrow;      // A rows: +8i
    const int brow = 16 * w + lrow;            // B rows: +8i

    #define STAGE_G(s, b)                                                     \
        do {                                                                  \
            int k0_ = 64 * (s);                                               \
            const u16* As_; int lda_; int ka_ = k0_;                          \
            if (SPLIT && k0_ >= 256) { As_ = A1; lda_ = lda1; ka_ = k0_ - 256; }\
            else { As_ = A0; lda_ = lda0; }                                   \
            _Pragma("unroll")                                                 \
            for (int i = 0; i < BM / 32; ++i)                                 \
                gload_lds16(As_ + (size_t)(m0 + arow + 8 * i) * lda_ + ka_ + swz * 8,\
                            &A_lds[b][(BM / 4) * w + 8 * i][0]);              \
            _Pragma("unroll")                                                 \
            for (int i = 0; i < 2; ++i)                                       \
                gload_lds16(W0 + (size_t)(n0 + brow + 8 * i) * ldw0 + k0_ + swz * 8,\
                            &B_lds[b][16 * w + 8 * i][0]);                    \
        } while (0)

    f32x4 acc[MS][2];
    #pragma unroll
    for (int i = 0; i < MS; ++i)
        #pragma unroll
        for (int j = 0; j < 2; ++j)
            acc[i][j] = (f32x4){0.f, 0.f, 0.f, 0.f};

    const int NS = K >> 6;
    int cur = 0, nxt = 1;
    STAGE_G(0, 0);

    for (int s = 0; s < NS; ++s) {
        if (s + 1 < NS) {
            STAGE_G(s + 1, nxt);
            if constexpr (BM == 128)
                asm volatile("s_waitcnt vmcnt(6)" ::: "memory");
            else
                asm volatile("s_waitcnt vmcnt(4)" ::: "memory");
        } else {
            asm volatile("s_waitcnt vmcnt(0)" ::: "memory");
        }
        __builtin_amdgcn_sched_barrier(0);
        __builtin_amdgcn_s_barrier();
        __builtin_amdgcn_sched_barrier(0);

        #pragma unroll
        for (int ks = 0; ks < 2; ++ks) {
            s16x8 af[MS], bfr[2];
            #pragma unroll
            for (int ms = 0; ms < MS; ++ms)
                af[ms] = *(const s16x8*)&A_lds[cur][wm + ms * 16 + lr]
                                              [((ks * 4 + lg) ^ r7) * 8];
            #pragma unroll
            for (int ns = 0; ns < 2; ++ns)
                bfr[ns] = *(const s16x8*)&B_lds[cur][wn + ns * 16 + lr]
                                               [((ks * 4 + lg) ^ r7) * 8];
            #pragma unroll
            for (int ms = 0; ms < MS; ++ms)
                #pragma unroll
                for (int ns = 0; ns < 2; ++ns)
                    acc[ms][ns] = mfma16(af[ms], bfr[ns], acc[ms][ns]);
        }
        cur = nxt;
        nxt = (nxt == 2) ? 0 : nxt + 1;
    }
    #undef STAGE_G

    #pragma unroll
    for (int ms = 0; ms < MS; ++ms) {
        #pragma unroll
        for (int ns = 0; ns < 2; ++ns) {
            int cg = n0 + wn + ns * 16 + lr;
            float bv = BIAS ? bias[cg] : 0.f;
            #pragma unroll
            for (int r = 0; r < 4; ++r) {
                int rg = m0 + wm + ms * 16 + lg * 4 + r;
                float val = acc[ms][ns][r] + bv;
                if (RESID) val += resid[(size_t)rg * N + cg];
                if (OUTMODE == 0) outf[(size_t)rg * ldo + cg] = val;
                else              outb[(size_t)rg * ldo + cg] = f2bf(val);
            }
        }
    }
}

// ---------------------------------------------------------------------------
// 3+4) Fused RoPE + V-transpose. Grid (64 n-blocks, 8 bh). Per block: 64 rows
// of head h. Writes Q,K (bf16 [bh][n][64], q scaled by 0.125*log2e) and Vt
// ([bh][64][n], PV-permuted: pos 32*kb+8*lg+j holds kv=32*kb+16*(j>>2)+4*lg+(j&3)).
// ---------------------------------------------------------------------------
__global__ __launch_bounds__(256) void rope_tv_kernel(
    const u16* __restrict__ qkv, const float* __restrict__ enc,
    u16* __restrict__ Qo, u16* __restrict__ Ko, u16* __restrict__ Vt)
{
    __shared__ u16 vt_lds[64][72];
    const int tid = threadIdx.x;
    const int bh = blockIdx.y, n0 = blockIdx.x * 64;
    const int b = bh >> 2, h = bh & 3;
    const float qs = 0.18033688011112042f;   // 0.125 * log2(e)

    #pragma unroll
    for (int it = 0; it < 8; ++it) {
        int task = it * 256 + tid;
        int r = task >> 5, t = task & 31;
        size_t grow = (size_t)(b * 4096 + n0 + r);
        const u16* base = qkv + grow * 768 + 3 * (h * 64) + 6 * t;
        ushort2 a01 = *(const ushort2*)(base);       // q0 k0
        ushort2 a23 = *(const ushort2*)(base + 2);   // v0 q1
        ushort2 a45 = *(const ushort2*)(base + 4);   // k1 v1
        float q0 = bf2f(a01.x), k0 = bf2f(a01.y);
        float q1 = bf2f(a23.y), k1 = bf2f(a45.x);
        const float* cb = enc + grow * 256 + h * 64 + 2 * t;
        float2 cosv = *(const float2*)cb;
        float2 sinv = *(const float2*)(cb + 2097152);
        float qr0 = (q0 * cosv.x - q1 * sinv.x) * qs;
        float qr1 = (q1 * cosv.y + q0 * sinv.y) * qs;
        float kr0 = k0 * cosv.x - k1 * sinv.x;
        float kr1 = k1 * cosv.y + k0 * sinv.y;
        size_t o = ((size_t)bh * 4096 + n0 + r) * 64 + 2 * t;
        *(unsigned*)(Qo + o) = cvt_pk_bf16(qr0, qr1);
        *(unsigned*)(Ko + o) = cvt_pk_bf16(kr0, kr1);
        vt_lds[r][2 * t]     = a23.x;
        vt_lds[r][2 * t + 1] = a45.y;
    }
    __syncthreads();
    #pragma unroll
    for (int i = 0; i < 2; ++i) {
        int c = tid + 256 * i;
        int d = c >> 3, ng = c & 7;
        int kb = ng >> 2, lg4 = ng & 3;
        int base = 32 * kb + 4 * lg4;
        unsigned w0 = pk2(vt_lds[base +  0][d], vt_lds[base +  1][d]);
        unsigned w1 = pk2(vt_lds[base +  2][d], vt_lds[base +  3][d]);
        unsigned w2 = pk2(vt_lds[base + 16][d], vt_lds[base + 17][d]);
        unsigned w3 = pk2(vt_lds[base + 18][d], vt_lds[base + 19][d]);
        uint4 o4 = make_uint4(w0, w1, w2, w3);
        *(uint4*)(Vt + ((size_t)bh * 64 + d) * 4096 + n0 + ng * 8) = o4;
    }
}

// ---------------------------------------------------------------------------
// 5) Flash attention, 32 q-rows/wave (round-12 config: best measured point on
// the LDS-traffic vs occupancy curve; 64 q/wave raised VGPR to 132 and
// collapsed occupancy). kv-split x4, swapped QK^T, fixed-shift softmax
// (C-init -24), MFMA row-sum. Static-buffer 2-phase unroll + setprio.
// ---------------------------------------------------------------------------
__global__ __launch_bounds__(256) void attn_kernel(
    const u16* __restrict__ Qp, const u16* __restrict__ Kp,
    const u16* __restrict__ Vtp, u16* __restrict__ Opart,
    float* __restrict__ Ssum)
{
    __shared__ u16 K_lds[2][64][64];   // 16 KB, linear
    __shared__ u16 V_lds[2][64][64];   // 16 KB, linear ([d][kv-permuted])
    const int tid = threadIdx.x;
    const int l = tid & 63, w = tid >> 6;
    const int lr = l & 15, lg = l >> 4;
    const int r7 = lr & 7;
    const int bh = blockIdx.y, z = blockIdx.z;
    const int n0 = blockIdx.x * 128 + w * 32;   // this wave's 32 q-rows

    const u16* Qb = Qp + ((size_t)bh * 4096 + n0) * 64;
    s16x8 qf[2][2];
    #pragma unroll
    for (int qt = 0; qt < 2; ++qt)
        #pragma unroll
        for (int dh = 0; dh < 2; ++dh)
            qf[qt][dh] = *(const s16x8*)(Qb + (qt * 16 + lr) * 64 + dh * 32 + lg * 8);

    const u16* Kb = Kp + (size_t)bh * 4096 * 64 + (size_t)z * 1024 * 64;
    const u16* Vb = Vtp + (size_t)bh * 64 * 4096 + z * 1024;

    const int xs0 = (lg ^ r7) * 8;
    const int xs1 = ((4 + lg) ^ r7) * 8;

    const int swz = (l & 7) ^ ((l >> 3) & 7);
    const int row0 = 16 * w + (l >> 3);
    const size_t koff0 = (size_t)row0 * 64 + swz * 8;
    const size_t koff1 = (size_t)(row0 + 8) * 64 + swz * 8;
    const size_t voff0 = (size_t)row0 * 4096 + swz * 8;
    const size_t voff1 = (size_t)(row0 + 8) * 4096 + swz * 8;

    #define STAGE(kt, b)                                                      \
        do {                                                                  \
            const u16* ks_ = Kb + (size_t)(kt) * 4096;                        \
            const u16* vs_ = Vb + (size_t)(kt) * 64;                          \
            gload_lds16(ks_ + koff0, &K_lds[b][16 * w][0]);                   \
            gload_lds16(ks_ + koff1, &K_lds[b][16 * w + 8][0]);               \
            gload_lds16(vs_ + voff0, &V_lds[b][16 * w][0]);                   \
            gload_lds16(vs_ + voff1, &V_lds[b][16 * w + 8][0]);               \
        } while (0)

    f32x4 O[2][4];
    #pragma unroll
    for (int qt = 0; qt < 2; ++qt)
        #pragma unroll
        for (int dv = 0; dv < 4; ++dv)
            O[qt][dv] = (f32x4){0.f, 0.f, 0.f, 0.f};
    f32x4 ssum[2];
    ssum[0] = (f32x4){0.f, 0.f, 0.f, 0.f};
    ssum[1] = (f32x4){0.f, 0.f, 0.f, 0.f};
    s16x8 ones;
    #pragma unroll
    for (int j = 0; j < 8; ++j) ones[j] = (short)0x3F80;   // bf16 1.0

    STAGE(0, 0);
    __syncthreads();   // drains DMA + barrier: buf0 ready

    #define PHASE(kt, CB, DO_STAGE)                                           \
        do {                                                                  \
            if (DO_STAGE) STAGE((kt) + 1, (CB) ^ 1);                          \
            f32x4 S[2][4];                                                    \
            __builtin_amdgcn_s_setprio(1);                                    \
            _Pragma("unroll")                                                 \
            for (int v4 = 0; v4 < 4; ++v4) {                                  \
                const int krow = v4 * 16 + lr;                                \
                s16x8 kf0 = *(const s16x8*)&K_lds[CB][krow][xs0];             \
                s16x8 kf1 = *(const s16x8*)&K_lds[CB][krow][xs1];             \
                _Pragma("unroll")                                             \
                for (int qt = 0; qt < 2; ++qt) {                              \
                    f32x4 zz = (f32x4){-24.f, -24.f, -24.f, -24.f};           \
                    zz = mfma16(kf0, qf[qt][0], zz);                          \
                    zz = mfma16(kf1, qf[qt][1], zz);                          \
                    S[qt][v4] = zz;                                           \
                }                                                             \
            }                                                                 \
            __builtin_amdgcn_s_setprio(0);                                    \
            s16x8 pa[2][2];                                                   \
            _Pragma("unroll")                                                 \
            for (int qt = 0; qt < 2; ++qt) {                                  \
                float p[4][4];                                                \
                _Pragma("unroll")                                             \
                for (int v4 = 0; v4 < 4; ++v4)                                \
                    _Pragma("unroll")                                         \
                    for (int r = 0; r < 4; ++r)                               \
                        p[v4][r] = fast_exp2(S[qt][v4][r]);                   \
                _Pragma("unroll")                                             \
                for (int kb = 0; kb < 2; ++kb) {                              \
                    union { unsigned u[4]; s16x8 v; } pu;                     \
                    pu.u[0] = cvt_pk_bf16(p[2*kb][0],   p[2*kb][1]);          \
                    pu.u[1] = cvt_pk_bf16(p[2*kb][2],   p[2*kb][3]);          \
                    pu.u[2] = cvt_pk_bf16(p[2*kb+1][0], p[2*kb+1][1]);        \
                    pu.u[3] = cvt_pk_bf16(p[2*kb+1][2], p[2*kb+1][3]);        \
                    pa[qt][kb] = pu.v;                                        \
                }                                                             \
            }                                                                 \
            __builtin_amdgcn_s_setprio(1);                                    \
            _Pragma("unroll")                                                 \
            for (int dv = 0; dv < 4; ++dv) {                                  \
                const int vrow = 16 * dv + lr;                                \
                s16x8 vf0 = *(const s16x8*)&V_lds[CB][vrow][xs0];             \
                s16x8 vf1 = *(const s16x8*)&V_lds[CB][vrow][xs1];             \
                _Pragma("unroll")                                             \
                for (int qt = 0; qt < 2; ++qt) {                              \
                    O[qt][dv] = mfma16(pa[qt][0], vf0, O[qt][dv]);            \
                    O[qt][dv] = mfma16(pa[qt][1], vf1, O[qt][dv]);            \
                }                                                             \
            }                                                                 \
            _Pragma("unroll")                                                 \
            for (int qt = 0; qt < 2; ++qt) {                                  \
                ssum[qt] = mfma16(pa[qt][0], ones, ssum[qt]);                 \
                ssum[qt] = mfma16(pa[qt][1], ones, ssum[qt]);                 \
            }                                                                 \
            __builtin_amdgcn_s_setprio(0);                                    \
            __syncthreads();                                                  \
        } while (0)

    #pragma unroll 1
    for (int kt = 0; kt < 16; kt += 2) {
        PHASE(kt, 0, true);
        PHASE(kt + 1, 1, kt < 14);
    }
    #undef PHASE
    #undef STAGE

    u16* Ob = Opart + ((size_t)(z * 8 + bh) * 4096 + n0) * 64;
    #pragma unroll
    for (int qt = 0; qt < 2; ++qt)
        #pragma unroll
        for (int dv = 0; dv < 4; ++dv)
            #pragma unroll
            for (int r = 0; r < 4; ++r)
                Ob[(size_t)(qt * 16 + 4 * lg + r) * 64 + 16 * dv + lr] =
                    f2bf(O[qt][dv][r]);
    if (lr == 0) {
        #pragma unroll
        for (int qt = 0; qt < 2; ++qt) {
            float4 sv = make_float4(ssum[qt][0], ssum[qt][1],
                                    ssum[qt][2], ssum[qt][3]);
            *(float4*)&Ssum[(size_t)(z * 8 + bh) * 4096 + n0 + qt * 16 + 4 * lg] = sv;
        }
    }
}

// ---------------------------------------------------------------------------
// 5b+6) Fused combine + out-projection: msg = combine(Opart,Ssum) @ out_w^T
// + out_b. Grid (128, 4), BM=64. Combine pre-pass fills A_lds [64][264]
// (padded: row stride 132 dwords = 4-bank shift -> 2-way free); B via 3-buf
// DMA, vmcnt(2). Kills the ctx global round-trip + one launch.
// ---------------------------------------------------------------------------
__global__ __launch_bounds__(256) void ctxproj_kernel(
    const u16* __restrict__ Opart, const float* __restrict__ Ssum,
    const u16* __restrict__ W0, const float* __restrict__ bias,
    u16* __restrict__ msg)
{
    __shared__ u16 A_lds[64][264];     // 33.8 KB combined ctx rows (padded)
    __shared__ u16 B_lds[3][64][64];   // 24 KB
    const int tid = threadIdx.x;
    const int l = tid & 63, w = tid >> 6;
    const int lr = l & 15, lg = l >> 4;
    const int r7 = lr & 7;
    const int m0 = blockIdx.x * 64, n0 = blockIdx.y * 64;
    const int wm = (w >> 1) * 32, wn = (w & 1) * 32;

    const int lrow = l >> 3;
    const int swz = (l & 7) ^ lrow;
    const int brow = 16 * w + lrow;

    #define STAGE_B(s, bb)                                                    \
        do {                                                                  \
            _Pragma("unroll")                                                 \
            for (int i = 0; i < 2; ++i)                                       \
                gload_lds16(W0 + (size_t)(n0 + brow + 8 * i) * 256 + 64 * (s) \
                                + swz * 8,                                    \
                            &B_lds[bb][16 * w + 8 * i][0]);                   \
        } while (0)

    STAGE_B(0, 0);

    // combine pre-pass: thread t -> row = t>>2, head h = t&3 (64-col stripe)
    {
        const int row = tid >> 2, h = tid & 3;
        const int rr = m0 + row;
        const int b = rr >> 12, n = rr & 4095;
        const size_t sb = (size_t)(b * 4 + h) * 4096 + n;
        float s = Ssum[sb] + Ssum[32768 + sb] + Ssum[65536 + sb] + Ssum[98304 + sb];
        float inv = 1.f / s;
        const size_t ob = sb * 64;
        #pragma unroll 2
        for (int j = 0; j < 8; ++j) {
            float acc[8];
            #pragma unroll
            for (int e = 0; e < 8; ++e) acc[e] = 0.f;
            #pragma unroll
            for (int z = 0; z < 4; ++z) {
                u16x8 ov = *(const u16x8*)(Opart + (size_t)z * 2097152 + ob + j * 8);
                #pragma unroll
                for (int e = 0; e < 8; ++e) acc[e] += bf2f(ov[e]);
            }
            uint4 o4 = make_uint4(cvt_pk_bf16(acc[0] * inv, acc[1] * inv),
                                  cvt_pk_bf16(acc[2] * inv, acc[3] * inv),
                                  cvt_pk_bf16(acc[4] * inv, acc[5] * inv),
                                  cvt_pk_bf16(acc[6] * inv, acc[7] * inv));
            *(uint4*)&A_lds[row][h * 64 + j * 8] = o4;
        }
    }
    __syncthreads();   // drains pre-pass + B buf0 DMA; A_lds visible

    f32x4 acc[2][2];
    #pragma unroll
    for (int i = 0; i < 2; ++i)
        #pragma unroll
        for (int j = 0; j < 2; ++j)
            acc[i][j] = (f32x4){0.f, 0.f, 0.f, 0.f};

    int cur = 0, nxt = 1;
    for (int s = 0; s < 4; ++s) {
        if (s + 1 < 4) {
            STAGE_B(s + 1, nxt);
            asm volatile("s_waitcnt vmcnt(2)" ::: "memory");
        } else {
            asm volatile("s_waitcnt vmcnt(0)" ::: "memory");
        }
        __builtin_amdgcn_sched_barrier(0);
        __builtin_amdgcn_s_barrier();
        __builtin_amdgcn_sched_barrier(0);

        #pragma unroll
        for (int ks = 0; ks < 2; ++ks) {
            s16x8 af[2], bfr[2];
            #pragma unroll
            for (int ms = 0; ms < 2; ++ms)
                af[ms] = *(const s16x8*)&A_lds[wm + ms * 16 + lr]
                                              [64 * s + (ks * 4 + lg) * 8];
            #pragma unroll
            for (int ns = 0; ns < 2; ++ns)
                bfr[ns] = *(const s16x8*)&B_lds[cur][wn + ns * 16 + lr]
                                               [((ks * 4 + lg) ^ r7) * 8];
            #pragma unroll
            for (int ms = 0; ms < 2; ++ms)
                #pragma unroll
                for (int ns = 0; ns < 2; ++ns)
                    acc[ms][ns] = mfma16(af[ms], bfr[ns], acc[ms][ns]);
        }
        cur = nxt;
        nxt = (nxt == 2) ? 0 : nxt + 1;
    }
    #undef STAGE_B

    #pragma unroll
    for (int ms = 0; ms < 2; ++ms) {
        #pragma unroll
        for (int ns = 0; ns < 2; ++ns) {
            int cg = n0 + wn + ns * 16 + lr;
            float bv = bias[cg];
            #pragma unroll
            for (int r = 0; r < 4; ++r) {
                int rg = m0 + wm + ms * 16 + lg * 4 + r;
                msg[(size_t)rg * 256 + cg] = f2bf(acc[ms][ns][r] + bv);
            }
        }
    }
}

// ---------------------------------------------------------------------------
// 8) LayerNorm(512) + exact GELU, wave per row; bf16 in (y1), bf16 out.
// ---------------------------------------------------------------------------
__global__ __launch_bounds__(256) void ln_gelu_kernel(
    const u16* __restrict__ y, const float* __restrict__ g,
    const float* __restrict__ bta, u16* __restrict__ o)
{
    int row = blockIdx.x * 4 + (threadIdx.x >> 6);
    int l = threadIdx.x & 63;
    const u16* yr = y + (size_t)row * 512 + l * 8;
    u16x8 uv = *(const u16x8*)yr;
    float v[8];
    #pragma unroll
    for (int j = 0; j < 8; ++j) v[j] = bf2f(uv[j]);
    float s = 0.f;
    #pragma unroll
    for (int j = 0; j < 8; ++j) s += v[j];
    #pragma unroll
    for (int off = 32; off; off >>= 1) s += __shfl_xor(s, off, 64);
    float mu = s * (1.f / 512.f);
    float q = 0.f;
    #pragma unroll
    for (int j = 0; j < 8; ++j) { float t = v[j] - mu; q += t * t; }
    #pragma unroll
    for (int off = 32; off; off >>= 1) q += __shfl_xor(q, off, 64);
    float rs = rsqrtf(q * (1.f / 512.f) + 1e-5f);
    u16 u[8];
    #pragma unroll
    for (int j = 0; j < 8; ++j) {
        float t = (v[j] - mu) * rs * g[l * 8 + j] + bta[l * 8 + j];
        t = t * 0.5f * (1.f + erff(t * 0.70710678118654752f));
        u[j] = f2bf(t);
    }
    uint4 o4 = make_uint4(pk2(u[0], u[1]), pk2(u[2], u[3]),
                          pk2(u[4], u[5]), pk2(u[6], u[7]));
    *(uint4*)(o + (size_t)row * 512 + l * 8) = o4;
}

// ---------------------------------------------------------------------------
extern "C" void kernel_launch(void* const* d_in, const int* in_sizes, int n_in,
                              void* d_out, int out_size, void* d_ws, size_t ws_size,
                              hipStream_t stream) {
    (void)in_sizes; (void)n_in; (void)out_size; (void)ws_size;
    const float* x    = (const float*)d_in[0];
    const float* enc  = (const float*)d_in[1];
    const float* wqkv = (const float*)d_in[2];
    const float* bqkv = (const float*)d_in[3];
    const float* wout = (const float*)d_in[4];
    const float* bout = (const float*)d_in[5];
    const float* w1   = (const float*)d_in[6];
    const float* b1   = (const float*)d_in[7];
    const float* lng  = (const float*)d_in[8];
    const float* lnb  = (const float*)d_in[9];
    const float* w2   = (const float*)d_in[10];
    const float* b2   = (const float*)d_in[11];
    float* out = (float*)d_out;
    char* ws = (char*)d_ws;

    u16*   xb    = (u16*)(ws + 0);              // 4 MB   bf16 x [8192][256]
    u16*   wqkvb = (u16*)(ws + 4194304);        // 384 KB
    u16*   woutb = (u16*)(ws + 4587520);        // 128 KB
    u16*   w1b   = (u16*)(ws + 4718592);        // 512 KB
    u16*   w2b   = (u16*)(ws + 5242880);        // 256 KB
    u16*   qkvb  = (u16*)(ws + 5505024);        // 12 MB  bf16 qkv [8192][768]
    u16*   OpartB= (u16*)(ws + 5505024);        // 16 MB  (reuse after rope_tv)
    u16*   y1bf  = (u16*)(ws + 5505024);        // 8 MB   (reuse after ctxproj)
    float* Ssum  = (float*)(ws + 22282240);     // 512 KB
    u16*   q     = (u16*)(ws + 30670848);       // 4 MB  [bh][n][64]
    u16*   k     = (u16*)(ws + 34865152);       // 4 MB
    u16*   vt    = (u16*)(ws + 43253760);       // 4 MB  [bh][64][n] (permuted)
    u16*   ybf   = q;                           // reuse q region after attn
    u16*   msg   = (u16*)(ws + 51642368);       // 4 MB

    conv_kernel<<<2688, 256, 0, stream>>>(x, wqkv, wout, w1, w2,
                                          xb, wqkvb, woutb, w1b, w2b);
    // qkv = x @ Wqkv^T + b  (bf16 out)
    gemm_kernel<1, false, false, true, 128><<<dim3(64, 12), 256, 0, stream>>>(
        xb, nullptr, wqkvb, bqkv, nullptr, nullptr, qkvb,
        8192, 768, 256, 256, 0, 256, 768);
    rope_tv_kernel<<<dim3(64, 8), 256, 0, stream>>>(qkvb, enc, q, k, vt);
    attn_kernel<<<dim3(32, 8, 4), 256, 0, stream>>>(q, k, vt, OpartB, Ssum);
    // msg = combine(Opart) @ out_w^T + out_b  (fused)
    ctxproj_kernel<<<dim3(128, 4), 256, 0, stream>>>(OpartB, Ssum, woutb, bout, msg);
    // y1 = [x | msg] @ ffn1^T + b1  (bf16 out)
    gemm_kernel<1, true, false, true, 128><<<dim3(64, 8), 256, 0, stream>>>(
        xb, msg, w1b, b1, nullptr, nullptr, y1bf,
        8192, 512, 512, 256, 256, 512, 512);
    ln_gelu_kernel<<<2048, 256, 0, stream>>>(y1bf, lng, lnb, ybf);
    // out = x + ybf @ ffn2^T + b2  (fp32 out, residual)
    gemm_kernel<0, false, true, true, 64><<<dim3(128, 4), 256, 0, stream>>>(
        ybf, nullptr, w2b, b2, x, out, nullptr,
        8192, 256, 512, 512, 0, 512, 256);
}

// Round 15
// 117.173 us; speedup vs baseline: 1.0630x; 1.0490x over previous
//
#include <hip/hip_runtime.h>
#include <hip/hip_bf16.h>

using u16 = unsigned short;
using u16x8 = __attribute__((ext_vector_type(8))) unsigned short;
using s16x4 = __attribute__((ext_vector_type(4))) short;   // 4 bf16
using s16x8 = __attribute__((ext_vector_type(8))) short;   // 8 bf16 (4 VGPRs)
using f32x4 = __attribute__((ext_vector_type(4))) float;   // MFMA accum

__device__ __forceinline__ f32x4 mfma16(s16x8 a, s16x8 b, f32x4 c) {
    return __builtin_amdgcn_mfma_f32_16x16x32_bf16(a, b, c, 0, 0, 0);
}

__device__ __forceinline__ u16 f2bf(float f) {
    union { float f; unsigned u; } v; v.f = f;
    unsigned r = v.u + 0x7FFFu + ((v.u >> 16) & 1u);   // RNE
    return (u16)(r >> 16);
}

__device__ __forceinline__ unsigned cvt_pk_bf16(float lo, float hi) {
    unsigned r;
    asm("v_cvt_pk_bf16_f32 %0, %1, %2" : "=v"(r) : "v"(lo), "v"(hi));
    return r;
}

__device__ __forceinline__ float fast_exp2(float x) {
    float r;
    asm("v_exp_f32 %0, %1" : "=v"(r) : "v"(x));   // denorm underflow -> 0
    return r;
}

__device__ __forceinline__ unsigned pk2(u16 a, u16 b) {
    return (unsigned)a | ((unsigned)b << 16);
}

__device__ __forceinline__ float bf2f(u16 u) {
    union { unsigned u; float f; } v; v.u = ((unsigned)u) << 16;
    return v.f;
}

// async global -> LDS DMA, 16 B per lane; dest = lds_base + lane*16 (linear)
__device__ __forceinline__ void gload_lds16(const u16* g, u16* l) {
    __builtin_amdgcn_global_load_lds(
        (const __attribute__((address_space(1))) void*)g,
        (__attribute__((address_space(3))) void*)l, 16, 0, 0);
}

// ---------------------------------------------------------------------------
// 1) fp32 -> bf16 conversion: x, 4 weight matrices, and enc (one launch).
// quad cumsums: x 524288 | wqkv 573440 | wout 589824 | w1 655360 | w2 688128
// | enc 1736704.  Grid 6784.
// ---------------------------------------------------------------------------
__global__ __launch_bounds__(256) void conv_kernel(
    const float* __restrict__ s0, const float* __restrict__ s1,
    const float* __restrict__ s2, const float* __restrict__ s3,
    const float* __restrict__ s4, const float* __restrict__ s5,
    u16* __restrict__ d0, u16* __restrict__ d1, u16* __restrict__ d2,
    u16* __restrict__ d3, u16* __restrict__ d4, u16* __restrict__ d5)
{
    int i = blockIdx.x * 256 + threadIdx.x;
    const float* s; u16* d; int off;
    if (i < 524288)      { s = s0; d = d0; off = i; }
    else if (i < 573440) { s = s1; d = d1; off = i - 524288; }
    else if (i < 589824) { s = s2; d = d2; off = i - 573440; }
    else if (i < 655360) { s = s3; d = d3; off = i - 589824; }
    else if (i < 688128) { s = s4; d = d4; off = i - 655360; }
    else                 { s = s5; d = d5; off = i - 688128; }
    float4 f = ((const float4*)s)[off];
    ushort4 u;
    u.x = f2bf(f.x); u.y = f2bf(f.y); u.z = f2bf(f.z); u.w = f2bf(f.w);
    ((ushort4*)d)[off] = u;
}

// ---------------------------------------------------------------------------
// Generic bf16 MFMA GEMM: out[M][N] = A[M][K] * W[N][K]^T (+bias) (+resid bf16)
// Tile BM x 64. T4 pipeline: global_load_lds into 3-buffer XOR-swizzled LDS,
// counted vmcnt, ONE raw s_barrier per K-step. A may be split at k=256.
// ---------------------------------------------------------------------------
template<int OUTMODE, bool SPLIT, bool RESID, bool BIAS, int BM>
__global__ __launch_bounds__(256) void gemm_kernel(
    const u16* __restrict__ A0, const u16* __restrict__ A1,
    const u16* __restrict__ W0, const float* __restrict__ bias,
    const u16* __restrict__ resid, float* __restrict__ outf,
    u16* __restrict__ outb,
    int M, int N, int K, int lda0, int lda1, int ldw0, int ldo)
{
    constexpr int MS = BM / 32;            // m-subtiles per wave
    __shared__ u16 A_lds[3][BM][64];
    __shared__ u16 B_lds[3][64][64];
    const int tid = threadIdx.x;
    const int l = tid & 63, w = tid >> 6;
    const int lr = l & 15, lg = l >> 4;
    const int r7 = lr & 7;
    const int m0 = blockIdx.x * BM, n0 = blockIdx.y * 64;
    const int wm = (w >> 1) * (BM / 2), wn = (w & 1) * 32;

    const int lrow = l >> 3;
    const int swz = (l & 7) ^ lrow;            // logical 16B-slot for this lane
    const int arow = (BM / 4) * w + lrow;      // A rows: +8i
    const int brow = 16 * w + lrow;            // B rows: +8i

    #define STAGE_G(s, b)                                                     \
        do {                                                                  \
            int k0_ = 64 * (s);                                               \
            const u16* As_; int lda_; int ka_ = k0_;                          \
            if (SPLIT && k0_ >= 256) { As_ = A1; lda_ = lda1; ka_ = k0_ - 256; }\
            else { As_ = A0; lda_ = lda0; }                                   \
            _Pragma("unroll")                                                 \
            for (int i = 0; i < BM / 32; ++i)                                 \
                gload_lds16(As_ + (size_t)(m0 + arow + 8 * i) * lda_ + ka_ + swz * 8,\
                            &A_lds[b][(BM / 4) * w + 8 * i][0]);              \
            _Pragma("unroll")                                                 \
            for (int i = 0; i < 2; ++i)                                       \
                gload_lds16(W0 + (size_t)(n0 + brow + 8 * i) * ldw0 + k0_ + swz * 8,\
                            &B_lds[b][16 * w + 8 * i][0]);                    \
        } while (0)

    f32x4 acc[MS][2];
    #pragma unroll
    for (int i = 0; i < MS; ++i)
        #pragma unroll
        for (int j = 0; j < 2; ++j)
            acc[i][j] = (f32x4){0.f, 0.f, 0.f, 0.f};

    const int NS = K >> 6;
    int cur = 0, nxt = 1;
    STAGE_G(0, 0);

    for (int s = 0; s < NS; ++s) {
        if (s + 1 < NS) {
            STAGE_G(s + 1, nxt);
            if constexpr (BM == 128)
                asm volatile("s_waitcnt vmcnt(6)" ::: "memory");
            else
                asm volatile("s_waitcnt vmcnt(4)" ::: "memory");
        } else {
            asm volatile("s_waitcnt vmcnt(0)" ::: "memory");
        }
        __builtin_amdgcn_sched_barrier(0);
        __builtin_amdgcn_s_barrier();
        __builtin_amdgcn_sched_barrier(0);

        #pragma unroll
        for (int ks = 0; ks < 2; ++ks) {
            s16x8 af[MS], bfr[2];
            #pragma unroll
            for (int ms = 0; ms < MS; ++ms)
                af[ms] = *(const s16x8*)&A_lds[cur][wm + ms * 16 + lr]
                                              [((ks * 4 + lg) ^ r7) * 8];
            #pragma unroll
            for (int ns = 0; ns < 2; ++ns)
                bfr[ns] = *(const s16x8*)&B_lds[cur][wn + ns * 16 + lr]
                                               [((ks * 4 + lg) ^ r7) * 8];
            #pragma unroll
            for (int ms = 0; ms < MS; ++ms)
                #pragma unroll
                for (int ns = 0; ns < 2; ++ns)
                    acc[ms][ns] = mfma16(af[ms], bfr[ns], acc[ms][ns]);
        }
        cur = nxt;
        nxt = (nxt == 2) ? 0 : nxt + 1;
    }
    #undef STAGE_G

    #pragma unroll
    for (int ms = 0; ms < MS; ++ms) {
        #pragma unroll
        for (int ns = 0; ns < 2; ++ns) {
            int cg = n0 + wn + ns * 16 + lr;
            float bv = BIAS ? bias[cg] : 0.f;
            #pragma unroll
            for (int r = 0; r < 4; ++r) {
                int rg = m0 + wm + ms * 16 + lg * 4 + r;
                float val = acc[ms][ns][r] + bv;
                if (RESID) val += bf2f(resid[(size_t)rg * N + cg]);
                if (OUTMODE == 0) outf[(size_t)rg * ldo + cg] = val;
                else              outb[(size_t)rg * ldo + cg] = f2bf(val);
            }
        }
    }
}

// ---------------------------------------------------------------------------
// 3+4) Fused RoPE + V-transpose (enc in bf16). Grid (64 n-blocks, 8 bh).
// Writes Q,K (bf16 [bh][n][64], q scaled by 0.125*log2e) and Vt
// ([bh][64][n], PV-permuted: pos 32*kb+8*lg+j holds kv=32*kb+16*(j>>2)+4*lg+(j&3)).
// ---------------------------------------------------------------------------
__global__ __launch_bounds__(256) void rope_tv_kernel(
    const u16* __restrict__ qkv, const u16* __restrict__ encb,
    u16* __restrict__ Qo, u16* __restrict__ Ko, u16* __restrict__ Vt)
{
    __shared__ u16 vt_lds[64][72];
    const int tid = threadIdx.x;
    const int bh = blockIdx.y, n0 = blockIdx.x * 64;
    const int b = bh >> 2, h = bh & 3;
    const float qs = 0.18033688011112042f;   // 0.125 * log2(e)

    #pragma unroll
    for (int it = 0; it < 8; ++it) {
        int task = it * 256 + tid;
        int r = task >> 5, t = task & 31;
        size_t grow = (size_t)(b * 4096 + n0 + r);
        const u16* base = qkv + grow * 768 + 3 * (h * 64) + 6 * t;
        ushort2 a01 = *(const ushort2*)(base);       // q0 k0
        ushort2 a23 = *(const ushort2*)(base + 2);   // v0 q1
        ushort2 a45 = *(const ushort2*)(base + 4);   // k1 v1
        float q0 = bf2f(a01.x), k0 = bf2f(a01.y);
        float q1 = bf2f(a23.y), k1 = bf2f(a45.x);
        const u16* cb = encb + grow * 256 + h * 64 + 2 * t;
        ushort2 c2 = *(const ushort2*)cb;
        ushort2 s2 = *(const ushort2*)(cb + 2097152);
        float cx = bf2f(c2.x), cy = bf2f(c2.y);
        float sx = bf2f(s2.x), sy = bf2f(s2.y);
        float qr0 = (q0 * cx - q1 * sx) * qs;
        float qr1 = (q1 * cy + q0 * sy) * qs;
        float kr0 = k0 * cx - k1 * sx;
        float kr1 = k1 * cy + k0 * sy;
        size_t o = ((size_t)bh * 4096 + n0 + r) * 64 + 2 * t;
        *(unsigned*)(Qo + o) = cvt_pk_bf16(qr0, qr1);
        *(unsigned*)(Ko + o) = cvt_pk_bf16(kr0, kr1);
        vt_lds[r][2 * t]     = a23.x;
        vt_lds[r][2 * t + 1] = a45.y;
    }
    __syncthreads();
    #pragma unroll
    for (int i = 0; i < 2; ++i) {
        int c = tid + 256 * i;
        int d = c >> 3, ng = c & 7;
        int kb = ng >> 2, lg4 = ng & 3;
        int base = 32 * kb + 4 * lg4;
        unsigned w0 = pk2(vt_lds[base +  0][d], vt_lds[base +  1][d]);
        unsigned w1 = pk2(vt_lds[base +  2][d], vt_lds[base +  3][d]);
        unsigned w2 = pk2(vt_lds[base + 16][d], vt_lds[base + 17][d]);
        unsigned w3 = pk2(vt_lds[base + 18][d], vt_lds[base + 19][d]);
        uint4 o4 = make_uint4(w0, w1, w2, w3);
        *(uint4*)(Vt + ((size_t)bh * 64 + d) * 4096 + n0 + ng * 8) = o4;
    }
}

// ---------------------------------------------------------------------------
// 5) Flash attention, 32 q-rows/wave (best measured point on the LDS-traffic
// vs occupancy curve). kv-split x4, swapped QK^T, fixed-shift softmax
// (C-init -24), MFMA row-sum. Static-buffer 2-phase unroll + setprio.
// ---------------------------------------------------------------------------
__global__ __launch_bounds__(256) void attn_kernel(
    const u16* __restrict__ Qp, const u16* __restrict__ Kp,
    const u16* __restrict__ Vtp, u16* __restrict__ Opart,
    float* __restrict__ Ssum)
{
    __shared__ u16 K_lds[2][64][64];   // 16 KB, linear
    __shared__ u16 V_lds[2][64][64];   // 16 KB, linear ([d][kv-permuted])
    const int tid = threadIdx.x;
    const int l = tid & 63, w = tid >> 6;
    const int lr = l & 15, lg = l >> 4;
    const int r7 = lr & 7;
    const int bh = blockIdx.y, z = blockIdx.z;
    const int n0 = blockIdx.x * 128 + w * 32;   // this wave's 32 q-rows

    const u16* Qb = Qp + ((size_t)bh * 4096 + n0) * 64;
    s16x8 qf[2][2];
    #pragma unroll
    for (int qt = 0; qt < 2; ++qt)
        #pragma unroll
        for (int dh = 0; dh < 2; ++dh)
            qf[qt][dh] = *(const s16x8*)(Qb + (qt * 16 + lr) * 64 + dh * 32 + lg * 8);

    const u16* Kb = Kp + (size_t)bh * 4096 * 64 + (size_t)z * 1024 * 64;
    const u16* Vb = Vtp + (size_t)bh * 64 * 4096 + z * 1024;

    const int xs0 = (lg ^ r7) * 8;
    const int xs1 = ((4 + lg) ^ r7) * 8;

    const int swz = (l & 7) ^ ((l >> 3) & 7);
    const int row0 = 16 * w + (l >> 3);
    const size_t koff0 = (size_t)row0 * 64 + swz * 8;
    const size_t koff1 = (size_t)(row0 + 8) * 64 + swz * 8;
    const size_t voff0 = (size_t)row0 * 4096 + swz * 8;
    const size_t voff1 = (size_t)(row0 + 8) * 4096 + swz * 8;

    #define STAGE(kt, b)                                                      \
        do {                                                                  \
            const u16* ks_ = Kb + (size_t)(kt) * 4096;                        \
            const u16* vs_ = Vb + (size_t)(kt) * 64;                          \
            gload_lds16(ks_ + koff0, &K_lds[b][16 * w][0]);                   \
            gload_lds16(ks_ + koff1, &K_lds[b][16 * w + 8][0]);               \
            gload_lds16(vs_ + voff0, &V_lds[b][16 * w][0]);                   \
            gload_lds16(vs_ + voff1, &V_lds[b][16 * w + 8][0]);               \
        } while (0)

    f32x4 O[2][4];
    #pragma unroll
    for (int qt = 0; qt < 2; ++qt)
        #pragma unroll
        for (int dv = 0; dv < 4; ++dv)
            O[qt][dv] = (f32x4){0.f, 0.f, 0.f, 0.f};
    f32x4 ssum[2];
    ssum[0] = (f32x4){0.f, 0.f, 0.f, 0.f};
    ssum[1] = (f32x4){0.f, 0.f, 0.f, 0.f};
    s16x8 ones;
    #pragma unroll
    for (int j = 0; j < 8; ++j) ones[j] = (short)0x3F80;   // bf16 1.0

    STAGE(0, 0);
    __syncthreads();   // drains DMA + barrier: buf0 ready

    #define PHASE(kt, CB, DO_STAGE)                                           \
        do {                                                                  \
            if (DO_STAGE) STAGE((kt) + 1, (CB) ^ 1);                          \
            f32x4 S[2][4];                                                    \
            __builtin_amdgcn_s_setprio(1);                                    \
            _Pragma("unroll")                                                 \
            for (int v4 = 0; v4 < 4; ++v4) {                                  \
                const int krow = v4 * 16 + lr;                                \
                s16x8 kf0 = *(const s16x8*)&K_lds[CB][krow][xs0];             \
                s16x8 kf1 = *(const s16x8*)&K_lds[CB][krow][xs1];             \
                _Pragma("unroll")                                             \
                for (int qt = 0; qt < 2; ++qt) {                              \
                    f32x4 zz = (f32x4){-24.f, -24.f, -24.f, -24.f};           \
                    zz = mfma16(kf0, qf[qt][0], zz);                          \
                    zz = mfma16(kf1, qf[qt][1], zz);                          \
                    S[qt][v4] = zz;                                           \
                }                                                             \
            }                                                                 \
            __builtin_amdgcn_s_setprio(0);                                    \
            s16x8 pa[2][2];                                                   \
            _Pragma("unroll")                                                 \
            for (int qt = 0; qt < 2; ++qt) {                                  \
                float p[4][4];                                                \
                _Pragma("unroll")                                             \
                for (int v4 = 0; v4 < 4; ++v4)                                \
                    _Pragma("unroll")                                         \
                    for (int r = 0; r < 4; ++r)                               \
                        p[v4][r] = fast_exp2(S[qt][v4][r]);                   \
                _Pragma("unroll")                                             \
                for (int kb = 0; kb < 2; ++kb) {                              \
                    union { unsigned u[4]; s16x8 v; } pu;                     \
                    pu.u[0] = cvt_pk_bf16(p[2*kb][0],   p[2*kb][1]);          \
                    pu.u[1] = cvt_pk_bf16(p[2*kb][2],   p[2*kb][3]);          \
                    pu.u[2] = cvt_pk_bf16(p[2*kb+1][0], p[2*kb+1][1]);        \
                    pu.u[3] = cvt_pk_bf16(p[2*kb+1][2], p[2*kb+1][3]);        \
                    pa[qt][kb] = pu.v;                                        \
                }                                                             \
            }                                                                 \
            __builtin_amdgcn_s_setprio(1);                                    \
            _Pragma("unroll")                                                 \
            for (int dv = 0; dv < 4; ++dv) {                                  \
                const int vrow = 16 * dv + lr;                                \
                s16x8 vf0 = *(const s16x8*)&V_lds[CB][vrow][xs0];             \
                s16x8 vf1 = *(const s16x8*)&V_lds[CB][vrow][xs1];             \
                _Pragma("unroll")                                             \
                for (int qt = 0; qt < 2; ++qt) {                              \
                    O[qt][dv] = mfma16(pa[qt][0], vf0, O[qt][dv]);            \
                    O[qt][dv] = mfma16(pa[qt][1], vf1, O[qt][dv]);            \
                }                                                             \
            }                                                                 \
            _Pragma("unroll")                                                 \
            for (int qt = 0; qt < 2; ++qt) {                                  \
                ssum[qt] = mfma16(pa[qt][0], ones, ssum[qt]);                 \
                ssum[qt] = mfma16(pa[qt][1], ones, ssum[qt]);                 \
            }                                                                 \
            __builtin_amdgcn_s_setprio(0);                                    \
            __syncthreads();                                                  \
        } while (0)

    #pragma unroll 1
    for (int kt = 0; kt < 16; kt += 2) {
        PHASE(kt, 0, true);
        PHASE(kt + 1, 1, kt < 14);
    }
    #undef PHASE
    #undef STAGE

    u16* Ob = Opart + ((size_t)(z * 8 + bh) * 4096 + n0) * 64;
    #pragma unroll
    for (int qt = 0; qt < 2; ++qt)
        #pragma unroll
        for (int dv = 0; dv < 4; ++dv)
            #pragma unroll
            for (int r = 0; r < 4; ++r)
                Ob[(size_t)(qt * 16 + 4 * lg + r) * 64 + 16 * dv + lr] =
                    f2bf(O[qt][dv][r]);
    if (lr == 0) {
        #pragma unroll
        for (int qt = 0; qt < 2; ++qt) {
            float4 sv = make_float4(ssum[qt][0], ssum[qt][1],
                                    ssum[qt][2], ssum[qt][3]);
            *(float4*)&Ssum[(size_t)(z * 8 + bh) * 4096 + n0 + qt * 16 + 4 * lg] = sv;
        }
    }
}

// ---------------------------------------------------------------------------
// 5b) Combine the four kv-split partials -> ctx (bf16 [b][n][256]).
// ---------------------------------------------------------------------------
__global__ __launch_bounds__(256) void combine_kernel(
    const u16* __restrict__ Opart, const float* __restrict__ Ssum,
    u16* __restrict__ ctx)
{
    int idx = blockIdx.x * 256 + threadIdx.x;    // 262144 = 32768 rows * 8 dc
    int rr = idx >> 3;            // bh*4096 + n
    int dc = (idx & 7) * 8;
    float s = Ssum[rr] + Ssum[32768 + rr] + Ssum[65536 + rr] + Ssum[98304 + rr];
    float inv = 1.f / s;
    float acc[8];
    #pragma unroll
    for (int j = 0; j < 8; ++j) acc[j] = 0.f;
    #pragma unroll
    for (int z = 0; z < 4; ++z) {
        u16x8 ov = *(const u16x8*)(Opart + ((size_t)z * 32768 + rr) * 64 + dc);
        #pragma unroll
        for (int j = 0; j < 8; ++j) acc[j] += bf2f(ov[j]);
    }
    #pragma unroll
    for (int j = 0; j < 8; ++j) acc[j] *= inv;
    int bh = rr >> 12, n = rr & 4095;
    int b = bh >> 2, h = bh & 3;
    uint4 o4 = make_uint4(cvt_pk_bf16(acc[0], acc[1]), cvt_pk_bf16(acc[2], acc[3]),
                          cvt_pk_bf16(acc[4], acc[5]), cvt_pk_bf16(acc[6], acc[7]));
    *(uint4*)(ctx + ((size_t)(b * 4096 + n)) * 256 + h * 64 + dc) = o4;
}

// ---------------------------------------------------------------------------
// 8) LayerNorm(512) + exact GELU, wave per row; bf16 in (y1), bf16 out.
// ---------------------------------------------------------------------------
__global__ __launch_bounds__(256) void ln_gelu_kernel(
    const u16* __restrict__ y, const float* __restrict__ g,
    const float* __restrict__ bta, u16* __restrict__ o)
{
    int row = blockIdx.x * 4 + (threadIdx.x >> 6);
    int l = threadIdx.x & 63;
    const u16* yr = y + (size_t)row * 512 + l * 8;
    u16x8 uv = *(const u16x8*)yr;
    float v[8];
    #pragma unroll
    for (int j = 0; j < 8; ++j) v[j] = bf2f(uv[j]);
    float s = 0.f;
    #pragma unroll
    for (int j = 0; j < 8; ++j) s += v[j];
    #pragma unroll
    for (int off = 32; off; off >>= 1) s += __shfl_xor(s, off, 64);
    float mu = s * (1.f / 512.f);
    float q = 0.f;
    #pragma unroll
    for (int j = 0; j < 8; ++j) { float t = v[j] - mu; q += t * t; }
    #pragma unroll
    for (int off = 32; off; off >>= 1) q += __shfl_xor(q, off, 64);
    float rs = rsqrtf(q * (1.f / 512.f) + 1e-5f);
    u16 u[8];
    #pragma unroll
    for (int j = 0; j < 8; ++j) {
        float t = (v[j] - mu) * rs * g[l * 8 + j] + bta[l * 8 + j];
        t = t * 0.5f * (1.f + erff(t * 0.70710678118654752f));
        u[j] = f2bf(t);
    }
    uint4 o4 = make_uint4(pk2(u[0], u[1]), pk2(u[2], u[3]),
                          pk2(u[4], u[5]), pk2(u[6], u[7]));
    *(uint4*)(o + (size_t)row * 512 + l * 8) = o4;
}

// ---------------------------------------------------------------------------
extern "C" void kernel_launch(void* const* d_in, const int* in_sizes, int n_in,
                              void* d_out, int out_size, void* d_ws, size_t ws_size,
                              hipStream_t stream) {
    (void)in_sizes; (void)n_in; (void)out_size; (void)ws_size;
    const float* x    = (const float*)d_in[0];
    const float* enc  = (const float*)d_in[1];
    const float* wqkv = (const float*)d_in[2];
    const float* bqkv = (const float*)d_in[3];
    const float* wout = (const float*)d_in[4];
    const float* bout = (const float*)d_in[5];
    const float* w1   = (const float*)d_in[6];
    const float* b1   = (const float*)d_in[7];
    const float* lng  = (const float*)d_in[8];
    const float* lnb  = (const float*)d_in[9];
    const float* w2   = (const float*)d_in[10];
    const float* b2   = (const float*)d_in[11];
    float* out = (float*)d_out;
    char* ws = (char*)d_ws;

    u16*   xb    = (u16*)(ws + 0);              // 4 MB   bf16 x [8192][256]
    u16*   wqkvb = (u16*)(ws + 4194304);        // 384 KB
    u16*   woutb = (u16*)(ws + 4587520);        // 128 KB
    u16*   w1b   = (u16*)(ws + 4718592);        // 512 KB
    u16*   w2b   = (u16*)(ws + 5242880);        // 256 KB
    u16*   qkvb  = (u16*)(ws + 5505024);        // 12 MB  bf16 qkv [8192][768]
    u16*   OpartB= (u16*)(ws + 5505024);        // 16 MB  (reuse after rope_tv)
    u16*   y1bf  = (u16*)(ws + 5505024);        // 8 MB   (reuse after combine)
    u16*   encb  = (u16*)(ws + 18087936);       // 8 MB   bf16 enc (dead after
                                                //        rope_tv; overlaps
                                                //        Opart tail + Ssum)
    float* Ssum  = (float*)(ws + 22282240);     // 512 KB
    u16*   q     = (u16*)(ws + 30670848);       // 4 MB  [bh][n][64]
    u16*   k     = (u16*)(ws + 34865152);       // 4 MB
    u16*   vt    = (u16*)(ws + 43253760);       // 4 MB  [bh][64][n] (permuted)
    u16*   ybf   = q;                           // reuse q region after attn
    u16*   ctx   = (u16*)(ws + 47448064);       // 4 MB
    u16*   msg   = (u16*)(ws + 51642368);       // 4 MB

    conv_kernel<<<6784, 256, 0, stream>>>(x, wqkv, wout, w1, w2, enc,
                                          xb, wqkvb, woutb, w1b, w2b, encb);
    // qkv = x @ Wqkv^T + b  (bf16 out)
    gemm_kernel<1, false, false, true, 128><<<dim3(64, 12), 256, 0, stream>>>(
        xb, nullptr, wqkvb, bqkv, nullptr, nullptr, qkvb,
        8192, 768, 256, 256, 0, 256, 768);
    rope_tv_kernel<<<dim3(64, 8), 256, 0, stream>>>(qkvb, encb, q, k, vt);
    attn_kernel<<<dim3(32, 8, 4), 256, 0, stream>>>(q, k, vt, OpartB, Ssum);
    combine_kernel<<<1024, 256, 0, stream>>>(OpartB, Ssum, ctx);
    // msg = ctx @ out_w^T + out_b  (bf16 out)
    gemm_kernel<1, false, false, true, 64><<<dim3(128, 4), 256, 0, stream>>>(
        ctx, nullptr, woutb, bout, nullptr, nullptr, msg,
        8192, 256, 256, 256, 0, 256, 256);
    // y1 = [x | msg] @ ffn1^T + b1  (bf16 out)
    gemm_kernel<1, true, false, true, 128><<<dim3(64, 8), 256, 0, stream>>>(
        xb, msg, w1b, b1, nullptr, nullptr, y1bf,
        8192, 512, 512, 256, 256, 512, 512);
    ln_gelu_kernel<<<2048, 256, 0, stream>>>(y1bf, lng, lnb, ybf);
    // out = xb + ybf @ ffn2^T + b2  (fp32 out, bf16 residual)
    gemm_kernel<0, false, true, true, 64><<<dim3(128, 4), 256, 0, stream>>>(
        ybf, nullptr, w2b, b2, xb, out, nullptr,
        8192, 256, 512, 512, 0, 512, 256);
}

// Round 16
// 116.206 us; speedup vs baseline: 1.0719x; 1.0083x over previous
//
#include <hip/hip_runtime.h>
#include <hip/hip_bf16.h>

using u16 = unsigned short;
using u16x8 = __attribute__((ext_vector_type(8))) unsigned short;
using s16x4 = __attribute__((ext_vector_type(4))) short;   // 4 bf16
using s16x8 = __attribute__((ext_vector_type(8))) short;   // 8 bf16 (4 VGPRs)
using f32x4 = __attribute__((ext_vector_type(4))) float;   // MFMA accum

__device__ __forceinline__ f32x4 mfma16(s16x8 a, s16x8 b, f32x4 c) {
    return __builtin_amdgcn_mfma_f32_16x16x32_bf16(a, b, c, 0, 0, 0);
}

__device__ __forceinline__ u16 f2bf(float f) {
    union { float f; unsigned u; } v; v.f = f;
    unsigned r = v.u + 0x7FFFu + ((v.u >> 16) & 1u);   // RNE
    return (u16)(r >> 16);
}

__device__ __forceinline__ unsigned cvt_pk_bf16(float lo, float hi) {
    unsigned r;
    asm("v_cvt_pk_bf16_f32 %0, %1, %2" : "=v"(r) : "v"(lo), "v"(hi));
    return r;
}

__device__ __forceinline__ float fast_exp2(float x) {
    float r;
    asm("v_exp_f32 %0, %1" : "=v"(r) : "v"(x));   // denorm underflow -> 0
    return r;
}

__device__ __forceinline__ unsigned pk2(u16 a, u16 b) {
    return (unsigned)a | ((unsigned)b << 16);
}

__device__ __forceinline__ float bf2f(u16 u) {
    union { unsigned u; float f; } v; v.u = ((unsigned)u) << 16;
    return v.f;
}

// async global -> LDS DMA, 16 B per lane; dest = lds_base + lane*16 (linear)
__device__ __forceinline__ void gload_lds16(const u16* g, u16* l) {
    __builtin_amdgcn_global_load_lds(
        (const __attribute__((address_space(1))) void*)g,
        (__attribute__((address_space(3))) void*)l, 16, 0, 0);
}

// ---------------------------------------------------------------------------
// 1) fp32 -> bf16 conversion of x and the 4 weight matrices (one launch).
// (enc is NOT converted: it's read exactly once -> conversion is net-negative)
// ---------------------------------------------------------------------------
__global__ __launch_bounds__(256) void conv_kernel(
    const float* __restrict__ s0, const float* __restrict__ s1,
    const float* __restrict__ s2, const float* __restrict__ s3,
    const float* __restrict__ s4,
    u16* __restrict__ d0, u16* __restrict__ d1, u16* __restrict__ d2,
    u16* __restrict__ d3, u16* __restrict__ d4)
{
    int i = blockIdx.x * 256 + threadIdx.x;
    const float* s; u16* d; int off;
    if (i < 524288)      { s = s0; d = d0; off = i; }
    else if (i < 573440) { s = s1; d = d1; off = i - 524288; }
    else if (i < 589824) { s = s2; d = d2; off = i - 573440; }
    else if (i < 655360) { s = s3; d = d3; off = i - 589824; }
    else                 { s = s4; d = d4; off = i - 655360; }
    float4 f = ((const float4*)s)[off];
    ushort4 u;
    u.x = f2bf(f.x); u.y = f2bf(f.y); u.z = f2bf(f.z); u.w = f2bf(f.w);
    ((ushort4*)d)[off] = u;
}

// ---------------------------------------------------------------------------
// Generic bf16 MFMA GEMM: out[M][N] = A[M][K] * W[N][K]^T (+bias) (+resid bf16)
// Tile BM x 64. T4 pipeline: global_load_lds into 3-buffer XOR-swizzled LDS,
// counted vmcnt, ONE raw s_barrier per K-step. A may be split at k=256.
// ---------------------------------------------------------------------------
template<int OUTMODE, bool SPLIT, bool RESID, bool BIAS, int BM>
__global__ __launch_bounds__(256) void gemm_kernel(
    const u16* __restrict__ A0, const u16* __restrict__ A1,
    const u16* __restrict__ W0, const float* __restrict__ bias,
    const u16* __restrict__ resid, float* __restrict__ outf,
    u16* __restrict__ outb,
    int M, int N, int K, int lda0, int lda1, int ldw0, int ldo)
{
    constexpr int MS = BM / 32;            // m-subtiles per wave
    __shared__ u16 A_lds[3][BM][64];
    __shared__ u16 B_lds[3][64][64];
    const int tid = threadIdx.x;
    const int l = tid & 63, w = tid >> 6;
    const int lr = l & 15, lg = l >> 4;
    const int r7 = lr & 7;
    const int m0 = blockIdx.x * BM, n0 = blockIdx.y * 64;
    const int wm = (w >> 1) * (BM / 2), wn = (w & 1) * 32;

    const int lrow = l >> 3;
    const int swz = (l & 7) ^ lrow;            // logical 16B-slot for this lane
    const int arow = (BM / 4) * w + lrow;      // A rows: +8i
    const int brow = 16 * w + lrow;            // B rows: +8i

    #define STAGE_G(s, b)                                                     \
        do {                                                                  \
            int k0_ = 64 * (s);                                               \
            const u16* As_; int lda_; int ka_ = k0_;                          \
            if (SPLIT && k0_ >= 256) { As_ = A1; lda_ = lda1; ka_ = k0_ - 256; }\
            else { As_ = A0; lda_ = lda0; }                                   \
            _Pragma("unroll")                                                 \
            for (int i = 0; i < BM / 32; ++i)                                 \
                gload_lds16(As_ + (size_t)(m0 + arow + 8 * i) * lda_ + ka_ + swz * 8,\
                            &A_lds[b][(BM / 4) * w + 8 * i][0]);              \
            _Pragma("unroll")                                                 \
            for (int i = 0; i < 2; ++i)                                       \
                gload_lds16(W0 + (size_t)(n0 + brow + 8 * i) * ldw0 + k0_ + swz * 8,\
                            &B_lds[b][16 * w + 8 * i][0]);                    \
        } while (0)

    f32x4 acc[MS][2];
    #pragma unroll
    for (int i = 0; i < MS; ++i)
        #pragma unroll
        for (int j = 0; j < 2; ++j)
            acc[i][j] = (f32x4){0.f, 0.f, 0.f, 0.f};

    const int NS = K >> 6;
    int cur = 0, nxt = 1;
    STAGE_G(0, 0);

    for (int s = 0; s < NS; ++s) {
        if (s + 1 < NS) {
            STAGE_G(s + 1, nxt);
            if constexpr (BM == 128)
                asm volatile("s_waitcnt vmcnt(6)" ::: "memory");
            else
                asm volatile("s_waitcnt vmcnt(4)" ::: "memory");
        } else {
            asm volatile("s_waitcnt vmcnt(0)" ::: "memory");
        }
        __builtin_amdgcn_sched_barrier(0);
        __builtin_amdgcn_s_barrier();
        __builtin_amdgcn_sched_barrier(0);

        #pragma unroll
        for (int ks = 0; ks < 2; ++ks) {
            s16x8 af[MS], bfr[2];
            #pragma unroll
            for (int ms = 0; ms < MS; ++ms)
                af[ms] = *(const s16x8*)&A_lds[cur][wm + ms * 16 + lr]
                                              [((ks * 4 + lg) ^ r7) * 8];
            #pragma unroll
            for (int ns = 0; ns < 2; ++ns)
                bfr[ns] = *(const s16x8*)&B_lds[cur][wn + ns * 16 + lr]
                                               [((ks * 4 + lg) ^ r7) * 8];
            #pragma unroll
            for (int ms = 0; ms < MS; ++ms)
                #pragma unroll
                for (int ns = 0; ns < 2; ++ns)
                    acc[ms][ns] = mfma16(af[ms], bfr[ns], acc[ms][ns]);
        }
        cur = nxt;
        nxt = (nxt == 2) ? 0 : nxt + 1;
    }
    #undef STAGE_G

    #pragma unroll
    for (int ms = 0; ms < MS; ++ms) {
        #pragma unroll
        for (int ns = 0; ns < 2; ++ns) {
            int cg = n0 + wn + ns * 16 + lr;
            float bv = BIAS ? bias[cg] : 0.f;
            #pragma unroll
            for (int r = 0; r < 4; ++r) {
                int rg = m0 + wm + ms * 16 + lg * 4 + r;
                float val = acc[ms][ns][r] + bv;
                if (RESID) val += bf2f(resid[(size_t)rg * N + cg]);
                if (OUTMODE == 0) outf[(size_t)rg * ldo + cg] = val;
                else              outb[(size_t)rg * ldo + cg] = f2bf(val);
            }
        }
    }
}

// ---------------------------------------------------------------------------
// 3+4) Fused RoPE + V-transpose (enc fp32, read once). Grid (64, 8 bh).
// Writes Q,K (bf16 [bh][n][64], q scaled by 0.125*log2e) and Vt
// ([bh][64][n], PV-permuted: pos 32*kb+8*lg+j holds kv=32*kb+16*(j>>2)+4*lg+(j&3)).
// ---------------------------------------------------------------------------
__global__ __launch_bounds__(256) void rope_tv_kernel(
    const u16* __restrict__ qkv, const float* __restrict__ enc,
    u16* __restrict__ Qo, u16* __restrict__ Ko, u16* __restrict__ Vt)
{
    __shared__ u16 vt_lds[64][72];
    const int tid = threadIdx.x;
    const int bh = blockIdx.y, n0 = blockIdx.x * 64;
    const int b = bh >> 2, h = bh & 3;
    const float qs = 0.18033688011112042f;   // 0.125 * log2(e)

    #pragma unroll
    for (int it = 0; it < 8; ++it) {
        int task = it * 256 + tid;
        int r = task >> 5, t = task & 31;
        size_t grow = (size_t)(b * 4096 + n0 + r);
        const u16* base = qkv + grow * 768 + 3 * (h * 64) + 6 * t;
        ushort2 a01 = *(const ushort2*)(base);       // q0 k0
        ushort2 a23 = *(const ushort2*)(base + 2);   // v0 q1
        ushort2 a45 = *(const ushort2*)(base + 4);   // k1 v1
        float q0 = bf2f(a01.x), k0 = bf2f(a01.y);
        float q1 = bf2f(a23.y), k1 = bf2f(a45.x);
        const float* cb = enc + grow * 256 + h * 64 + 2 * t;
        float2 cosv = *(const float2*)cb;
        float2 sinv = *(const float2*)(cb + 2097152);
        float qr0 = (q0 * cosv.x - q1 * sinv.x) * qs;
        float qr1 = (q1 * cosv.y + q0 * sinv.y) * qs;
        float kr0 = k0 * cosv.x - k1 * sinv.x;
        float kr1 = k1 * cosv.y + k0 * sinv.y;
        size_t o = ((size_t)bh * 4096 + n0 + r) * 64 + 2 * t;
        *(unsigned*)(Qo + o) = cvt_pk_bf16(qr0, qr1);
        *(unsigned*)(Ko + o) = cvt_pk_bf16(kr0, kr1);
        vt_lds[r][2 * t]     = a23.x;
        vt_lds[r][2 * t + 1] = a45.y;
    }
    __syncthreads();
    #pragma unroll
    for (int i = 0; i < 2; ++i) {
        int c = tid + 256 * i;
        int d = c >> 3, ng = c & 7;
        int kb = ng >> 2, lg4 = ng & 3;
        int base = 32 * kb + 4 * lg4;
        unsigned w0 = pk2(vt_lds[base +  0][d], vt_lds[base +  1][d]);
        unsigned w1 = pk2(vt_lds[base +  2][d], vt_lds[base +  3][d]);
        unsigned w2 = pk2(vt_lds[base + 16][d], vt_lds[base + 17][d]);
        unsigned w3 = pk2(vt_lds[base + 18][d], vt_lds[base + 19][d]);
        uint4 o4 = make_uint4(w0, w1, w2, w3);
        *(uint4*)(Vt + ((size_t)bh * 64 + d) * 4096 + n0 + ng * 8) = o4;
    }
}

// ---------------------------------------------------------------------------
// 5) Flash attention, 32 q-rows/wave (best measured point on the LDS-traffic
// vs occupancy curve). kv-split x4, swapped QK^T, fixed-shift softmax
// (C-init -24), MFMA row-sum. Static-buffer 2-phase unroll + setprio.
// ---------------------------------------------------------------------------
__global__ __launch_bounds__(256) void attn_kernel(
    const u16* __restrict__ Qp, const u16* __restrict__ Kp,
    const u16* __restrict__ Vtp, u16* __restrict__ Opart,
    float* __restrict__ Ssum)
{
    __shared__ u16 K_lds[2][64][64];   // 16 KB, linear
    __shared__ u16 V_lds[2][64][64];   // 16 KB, linear ([d][kv-permuted])
    const int tid = threadIdx.x;
    const int l = tid & 63, w = tid >> 6;
    const int lr = l & 15, lg = l >> 4;
    const int r7 = lr & 7;
    const int bh = blockIdx.y, z = blockIdx.z;
    const int n0 = blockIdx.x * 128 + w * 32;   // this wave's 32 q-rows

    const u16* Qb = Qp + ((size_t)bh * 4096 + n0) * 64;
    s16x8 qf[2][2];
    #pragma unroll
    for (int qt = 0; qt < 2; ++qt)
        #pragma unroll
        for (int dh = 0; dh < 2; ++dh)
            qf[qt][dh] = *(const s16x8*)(Qb + (qt * 16 + lr) * 64 + dh * 32 + lg * 8);

    const u16* Kb = Kp + (size_t)bh * 4096 * 64 + (size_t)z * 1024 * 64;
    const u16* Vb = Vtp + (size_t)bh * 64 * 4096 + z * 1024;

    const int xs0 = (lg ^ r7) * 8;
    const int xs1 = ((4 + lg) ^ r7) * 8;

    const int swz = (l & 7) ^ ((l >> 3) & 7);
    const int row0 = 16 * w + (l >> 3);
    const size_t koff0 = (size_t)row0 * 64 + swz * 8;
    const size_t koff1 = (size_t)(row0 + 8) * 64 + swz * 8;
    const size_t voff0 = (size_t)row0 * 4096 + swz * 8;
    const size_t voff1 = (size_t)(row0 + 8) * 4096 + swz * 8;

    #define STAGE(kt, b)                                                      \
        do {                                                                  \
            const u16* ks_ = Kb + (size_t)(kt) * 4096;                        \
            const u16* vs_ = Vb + (size_t)(kt) * 64;                          \
            gload_lds16(ks_ + koff0, &K_lds[b][16 * w][0]);                   \
            gload_lds16(ks_ + koff1, &K_lds[b][16 * w + 8][0]);               \
            gload_lds16(vs_ + voff0, &V_lds[b][16 * w][0]);                   \
            gload_lds16(vs_ + voff1, &V_lds[b][16 * w + 8][0]);               \
        } while (0)

    f32x4 O[2][4];
    #pragma unroll
    for (int qt = 0; qt < 2; ++qt)
        #pragma unroll
        for (int dv = 0; dv < 4; ++dv)
            O[qt][dv] = (f32x4){0.f, 0.f, 0.f, 0.f};
    f32x4 ssum[2];
    ssum[0] = (f32x4){0.f, 0.f, 0.f, 0.f};
    ssum[1] = (f32x4){0.f, 0.f, 0.f, 0.f};
    s16x8 ones;
    #pragma unroll
    for (int j = 0; j < 8; ++j) ones[j] = (short)0x3F80;   // bf16 1.0

    STAGE(0, 0);
    __syncthreads();   // drains DMA + barrier: buf0 ready

    #define PHASE(kt, CB, DO_STAGE)                                           \
        do {                                                                  \
            if (DO_STAGE) STAGE((kt) + 1, (CB) ^ 1);                          \
            f32x4 S[2][4];                                                    \
            __builtin_amdgcn_s_setprio(1);                                    \
            _Pragma("unroll")                                                 \
            for (int v4 = 0; v4 < 4; ++v4) {                                  \
                const int krow = v4 * 16 + lr;                                \
                s16x8 kf0 = *(const s16x8*)&K_lds[CB][krow][xs0];             \
                s16x8 kf1 = *(const s16x8*)&K_lds[CB][krow][xs1];             \
                _Pragma("unroll")                                             \
                for (int qt = 0; qt < 2; ++qt) {                              \
                    f32x4 zz = (f32x4){-24.f, -24.f, -24.f, -24.f};           \
                    zz = mfma16(kf0, qf[qt][0], zz);                          \
                    zz = mfma16(kf1, qf[qt][1], zz);                          \
                    S[qt][v4] = zz;                                           \
                }                                                             \
            }                                                                 \
            __builtin_amdgcn_s_setprio(0);                                    \
            s16x8 pa[2][2];                                                   \
            _Pragma("unroll")                                                 \
            for (int qt = 0; qt < 2; ++qt) {                                  \
                float p[4][4];                                                \
                _Pragma("unroll")                                             \
                for (int v4 = 0; v4 < 4; ++v4)                                \
                    _Pragma("unroll")                                         \
                    for (int r = 0; r < 4; ++r)                               \
                        p[v4][r] = fast_exp2(S[qt][v4][r]);                   \
                _Pragma("unroll")                                             \
                for (int kb = 0; kb < 2; ++kb) {                              \
                    union { unsigned u[4]; s16x8 v; } pu;                     \
                    pu.u[0] = cvt_pk_bf16(p[2*kb][0],   p[2*kb][1]);          \
                    pu.u[1] = cvt_pk_bf16(p[2*kb][2],   p[2*kb][3]);          \
                    pu.u[2] = cvt_pk_bf16(p[2*kb+1][0], p[2*kb+1][1]);        \
                    pu.u[3] = cvt_pk_bf16(p[2*kb+1][2], p[2*kb+1][3]);        \
                    pa[qt][kb] = pu.v;                                        \
                }                                                             \
            }                                                                 \
            __builtin_amdgcn_s_setprio(1);                                    \
            _Pragma("unroll")                                                 \
            for (int dv = 0; dv < 4; ++dv) {                                  \
                const int vrow = 16 * dv + lr;                                \
                s16x8 vf0 = *(const s16x8*)&V_lds[CB][vrow][xs0];             \
                s16x8 vf1 = *(const s16x8*)&V_lds[CB][vrow][xs1];             \
                _Pragma("unroll")                                             \
                for (int qt = 0; qt < 2; ++qt) {                              \
                    O[qt][dv] = mfma16(pa[qt][0], vf0, O[qt][dv]);            \
                    O[qt][dv] = mfma16(pa[qt][1], vf1, O[qt][dv]);            \
                }                                                             \
            }                                                                 \
            _Pragma("unroll")                                                 \
            for (int qt = 0; qt < 2; ++qt) {                                  \
                ssum[qt] = mfma16(pa[qt][0], ones, ssum[qt]);                 \
                ssum[qt] = mfma16(pa[qt][1], ones, ssum[qt]);                 \
            }                                                                 \
            __builtin_amdgcn_s_setprio(0);                                    \
            __syncthreads();                                                  \
        } while (0)

    #pragma unroll 1
    for (int kt = 0; kt < 16; kt += 2) {
        PHASE(kt, 0, true);
        PHASE(kt + 1, 1, kt < 14);
    }
    #undef PHASE
    #undef STAGE

    u16* Ob = Opart + ((size_t)(z * 8 + bh) * 4096 + n0) * 64;
    #pragma unroll
    for (int qt = 0; qt < 2; ++qt)
        #pragma unroll
        for (int dv = 0; dv < 4; ++dv)
            #pragma unroll
            for (int r = 0; r < 4; ++r)
                Ob[(size_t)(qt * 16 + 4 * lg + r) * 64 + 16 * dv + lr] =
                    f2bf(O[qt][dv][r]);
    if (lr == 0) {
        #pragma unroll
        for (int qt = 0; qt < 2; ++qt) {
            float4 sv = make_float4(ssum[qt][0], ssum[qt][1],
                                    ssum[qt][2], ssum[qt][3]);
            *(float4*)&Ssum[(size_t)(z * 8 + bh) * 4096 + n0 + qt * 16 + 4 * lg] = sv;
        }
    }
}

// ---------------------------------------------------------------------------
// 5b) Combine the four kv-split partials -> ctx (bf16 [b][n][256]).
// ---------------------------------------------------------------------------
__global__ __launch_bounds__(256) void combine_kernel(
    const u16* __restrict__ Opart, const float* __restrict__ Ssum,
    u16* __restrict__ ctx)
{
    int idx = blockIdx.x * 256 + threadIdx.x;    // 262144 = 32768 rows * 8 dc
    int rr = idx >> 3;            // bh*4096 + n
    int dc = (idx & 7) * 8;
    float s = Ssum[rr] + Ssum[32768 + rr] + Ssum[65536 + rr] + Ssum[98304 + rr];
    float inv = 1.f / s;
    float acc[8];
    #pragma unroll
    for (int j = 0; j < 8; ++j) acc[j] = 0.f;
    #pragma unroll
    for (int z = 0; z < 4; ++z) {
        u16x8 ov = *(const u16x8*)(Opart + ((size_t)z * 32768 + rr) * 64 + dc);
        #pragma unroll
        for (int j = 0; j < 8; ++j) acc[j] += bf2f(ov[j]);
    }
    #pragma unroll
    for (int j = 0; j < 8; ++j) acc[j] *= inv;
    int bh = rr >> 12, n = rr & 4095;
    int b = bh >> 2, h = bh & 3;
    uint4 o4 = make_uint4(cvt_pk_bf16(acc[0], acc[1]), cvt_pk_bf16(acc[2], acc[3]),
                          cvt_pk_bf16(acc[4], acc[5]), cvt_pk_bf16(acc[6], acc[7]));
    *(uint4*)(ctx + ((size_t)(b * 4096 + n)) * 256 + h * 64 + dc) = o4;
}

// ---------------------------------------------------------------------------
// 8) LayerNorm(512) + exact GELU, wave per row; bf16 in (y1), bf16 out.
// ---------------------------------------------------------------------------
__global__ __launch_bounds__(256) void ln_gelu_kernel(
    const u16* __restrict__ y, const float* __restrict__ g,
    const float* __restrict__ bta, u16* __restrict__ o)
{
    int row = blockIdx.x * 4 + (threadIdx.x >> 6);
    int l = threadIdx.x & 63;
    const u16* yr = y + (size_t)row * 512 + l * 8;
    u16x8 uv = *(const u16x8*)yr;
    float v[8];
    #pragma unroll
    for (int j = 0; j < 8; ++j) v[j] = bf2f(uv[j]);
    float s = 0.f;
    #pragma unroll
    for (int j = 0; j < 8; ++j) s += v[j];
    #pragma unroll
    for (int off = 32; off; off >>= 1) s += __shfl_xor(s, off, 64);
    float mu = s * (1.f / 512.f);
    float q = 0.f;
    #pragma unroll
    for (int j = 0; j < 8; ++j) { float t = v[j] - mu; q += t * t; }
    #pragma unroll
    for (int off = 32; off; off >>= 1) q += __shfl_xor(q, off, 64);
    float rs = rsqrtf(q * (1.f / 512.f) + 1e-5f);
    u16 u[8];
    #pragma unroll
    for (int j = 0; j < 8; ++j) {
        float t = (v[j] - mu) * rs * g[l * 8 + j] + bta[l * 8 + j];
        t = t * 0.5f * (1.f + erff(t * 0.70710678118654752f));
        u[j] = f2bf(t);
    }
    uint4 o4 = make_uint4(pk2(u[0], u[1]), pk2(u[2], u[3]),
                          pk2(u[4], u[5]), pk2(u[6], u[7]));
    *(uint4*)(o + (size_t)row * 512 + l * 8) = o4;
}

// ---------------------------------------------------------------------------
extern "C" void kernel_launch(void* const* d_in, const int* in_sizes, int n_in,
                              void* d_out, int out_size, void* d_ws, size_t ws_size,
                              hipStream_t stream) {
    (void)in_sizes; (void)n_in; (void)out_size; (void)ws_size;
    const float* x    = (const float*)d_in[0];
    const float* enc  = (const float*)d_in[1];
    const float* wqkv = (const float*)d_in[2];
    const float* bqkv = (const float*)d_in[3];
    const float* wout = (const float*)d_in[4];
    const float* bout = (const float*)d_in[5];
    const float* w1   = (const float*)d_in[6];
    const float* b1   = (const float*)d_in[7];
    const float* lng  = (const float*)d_in[8];
    const float* lnb  = (const float*)d_in[9];
    const float* w2   = (const float*)d_in[10];
    const float* b2   = (const float*)d_in[11];
    float* out = (float*)d_out;
    char* ws = (char*)d_ws;

    u16*   xb    = (u16*)(ws + 0);              // 4 MB   bf16 x [8192][256]
    u16*   wqkvb = (u16*)(ws + 4194304);        // 384 KB
    u16*   woutb = (u16*)(ws + 4587520);        // 128 KB
    u16*   w1b   = (u16*)(ws + 4718592);        // 512 KB
    u16*   w2b   = (u16*)(ws + 5242880);        // 256 KB
    u16*   qkvb  = (u16*)(ws + 5505024);        // 12 MB  bf16 qkv [8192][768]
    u16*   OpartB= (u16*)(ws + 5505024);        // 16 MB  (reuse after rope_tv)
    u16*   y1bf  = (u16*)(ws + 5505024);        // 8 MB   (reuse after combine)
    float* Ssum  = (float*)(ws + 22282240);     // 512 KB
    u16*   q     = (u16*)(ws + 30670848);       // 4 MB  [bh][n][64]
    u16*   k     = (u16*)(ws + 34865152);       // 4 MB
    u16*   vt    = (u16*)(ws + 43253760);       // 4 MB  [bh][64][n] (permuted)
    u16*   ybf   = q;                           // reuse q region after attn
    u16*   ctx   = (u16*)(ws + 47448064);       // 4 MB
    u16*   msg   = (u16*)(ws + 51642368);       // 4 MB

    conv_kernel<<<2688, 256, 0, stream>>>(x, wqkv, wout, w1, w2,
                                          xb, wqkvb, woutb, w1b, w2b);
    // qkv = x @ Wqkv^T + b  (bf16 out)
    gemm_kernel<1, false, false, true, 128><<<dim3(64, 12), 256, 0, stream>>>(
        xb, nullptr, wqkvb, bqkv, nullptr, nullptr, qkvb,
        8192, 768, 256, 256, 0, 256, 768);
    rope_tv_kernel<<<dim3(64, 8), 256, 0, stream>>>(qkvb, enc, q, k, vt);
    attn_kernel<<<dim3(32, 8, 4), 256, 0, stream>>>(q, k, vt, OpartB, Ssum);
    combine_kernel<<<1024, 256, 0, stream>>>(OpartB, Ssum, ctx);
    // msg = ctx @ out_w^T + out_b  (bf16 out)
    gemm_kernel<1, false, false, true, 64><<<dim3(128, 4), 256, 0, stream>>>(
        ctx, nullptr, woutb, bout, nullptr, nullptr, msg,
        8192, 256, 256, 256, 0, 256, 256);
    // y1 = [x | msg] @ ffn1^T + b1  (bf16 out)
    gemm_kernel<1, true, false, true, 128><<<dim3(64, 8), 256, 0, stream>>>(
        xb, msg, w1b, b1, nullptr, nullptr, y1bf,
        8192, 512, 512, 256, 256, 512, 512);
    ln_gelu_kernel<<<2048, 256, 0, stream>>>(y1bf, lng, lnb, ybf);
    // out = xb + ybf @ ffn2^T + b2  (fp32 out, bf16 residual)
    gemm_kernel<0, false, true, true, 64><<<dim3(128, 4), 256, 0, stream>>>(
        ybf, nullptr, w2b, b2, xb, out, nullptr,
        8192, 256, 512, 512, 0, 512, 256);
}